// Round 5
// baseline (164.163 us; speedup 1.0000x reference)
//
#include <hip/hip_runtime.h>
#include <math.h>

#define NN 500
#define NE 64
#define BATCH 8
#define RR 15
#define PW 31            // 2R+1
#define CAN 200
#define OHW 198
#define TWO_PI_F 6.28318530717958647692f
// k_setup must cover canvas (320000) + psf_sums (64) + kern (49) AND NN*NN.
#define SETUP_N (BATCH * CAN * CAN + NE + 49)

// --- MFMA prop-rows parameters ---------------------------------------------
// kappa = 2u + p (p=0 re, p=1 im), u padded 500->512 => K = 1024 = 16 chunks x 64
#define BCH 16                     // K-chunks total (8 per K-half)
#define BKC 64                     // kappa per chunk
#define BSTR 72                    // padded row stride (f16; 144 B -> quad stride 9)
#define BG_CHUNK (2 * 64 * BSTR)   // f16 elems per chunk (hi+lo planes) = 9216
#define ASCALE (1.0f / 64.0f)      // A pre-scale (f16 range safety); undone in k_prop_cols
// part: [z][v][64 nu] floats — nu fastest, 62 useful + 2 pad = 256 B region

using f16x8 = __attribute__((ext_vector_type(8))) _Float16;
using f32x16 = __attribute__((ext_vector_type(16))) float;

// Fast accurate sincos for |theta| up to ~1200 rad: Cody-Waite 2-term
// reduction + hardware v_sin/v_cos on the reduced |r| <= pi argument.
__device__ __forceinline__ void fast_sincos_red(float theta, float* s, float* c) {
    const float INV2PI = 0.15915494309189535f;
    const float PI2_HI = 6.28318548202514648f;   // f32(2*pi)
    const float PI2_LO = -1.7484556e-7f;         // 2*pi - PI2_HI
    float n = rintf(theta * INV2PI);
    float r = fmaf(n, -PI2_HI, theta);
    r = fmaf(n, -PI2_LO, r);
    *s = __sinf(r);
    *c = __cosf(r);
}

// ---------------------------------------------------------------------------
// K_setup: K*GAMMA table (f64 sqrt path), 500-pt twiddle table, blur-kernel
// coefficients, canvas+psf_sums zero, AND (fused, was k_setup_b) the f16
// hi/lo twiddle matrix Bg for the MFMA partial-IDFT:
//   B[kappa][nu]: kappa = 2u+p, nu = 2*(r-235)+q (q=0 re-col, q=1 im-col)
//     q=0: p=0 ->  W.re   p=1 -> -W.im
//     q=1: p=0 ->  W.im   p=1 ->  W.re        (W = e^{+2pi i u r / 500})
// Stored [chunk=16][hi/lo][nu=64][BSTR=72 kappa-local].
// GRID MUST COVER SETUP_N.
// ---------------------------------------------------------------------------
__global__ void k_setup(const float* __restrict__ std_u,
                        float* __restrict__ kgamma,
                        float2* __restrict__ tw,
                        float* __restrict__ kern,
                        float* __restrict__ canvas,
                        float* __restrict__ psf_sums,
                        _Float16* __restrict__ Bg) {
    int idx = blockIdx.x * blockDim.x + threadIdx.x;
    if (idx < NN) {
        double th = 2.0 * M_PI * (double)idx / (double)NN;
        tw[idx] = make_float2((float)cos(th), (float)sin(th));
    }
    if (idx < BCH * 64 * BSTR) {   // fused Bg generation (independent window)
        int c = idx / (64 * BSTR);
        int rem = idx % (64 * BSTR);
        int nu = rem / BSTR, j = rem % BSTR;
        float hi = 0.f, lo = 0.f;
        int kap = c * BKC + j;
        if (j < BKC && kap < 2 * NN) {
            int u = kap >> 1, p = kap & 1;
            int ri = nu >> 1, q = nu & 1;
            int r = 235 + ri;             // ri=31 -> dummy col pair (pad)
            int m = (u * r) % NN;
            double th = 2.0 * M_PI * (double)m / (double)NN;
            double wre = cos(th), wim = sin(th);
            double val = (q == 0) ? ((p == 0) ? wre : -wim)
                                  : ((p == 0) ? wim : wre);
            float x = (float)val;
            _Float16 h = (_Float16)x;
            hi = (float)h;
            lo = x - (float)h;
        }
        size_t base = (size_t)c * BG_CHUNK + (size_t)nu * BSTR + j;
        Bg[base] = (_Float16)hi;
        Bg[base + (size_t)64 * BSTR] = (_Float16)lo;
    }
    if (idx < BATCH * CAN * CAN) canvas[idx] = 0.f;
    if (idx >= BATCH * CAN * CAN && idx < BATCH * CAN * CAN + NE)
        psf_sums[idx - BATCH * CAN * CAN] = 0.f;
    if (idx >= BATCH * CAN * CAN + NE && idx < SETUP_N) {
        int t = idx - (BATCH * CAN * CAN + NE);
        float stdv = 0.8f + 0.4f * std_u[0];
        float s2 = stdv * stdv;
        int a = t / 7 - 3, b = t % 7 - 3;
        float g = (float)exp(-0.5 * (double)(a * a + b * b));
        kern[t] = (1.0f / (2.0f * (float)M_PI * s2)) * powf(g, 1.0f / s2);
    }
    if (idx >= NN * NN) return;
    int i = idx / NN, j = idx % NN;
    double fy = (double)((i < 250) ? i : i - 500) * 2000.0;
    double fx = (double)((j < 250) ? j : j - 500) * 2000.0;
    double a = 5.32e-7 * fx;
    double b = 5.32e-7 * fy;
    double g = 1.0 - a * a - b * b;
    g = (g > 0.0) ? sqrt(g) : 0.0;
    float Kf = (float)(2.0 * M_PI * 1.0 / 5.32e-7);
    kgamma[idx] = Kf * (float)g;
}

// ---------------------------------------------------------------------------
// 500-pt forward DFT via Cooley-Tukey 20x25. Shared stages helper.
// ---------------------------------------------------------------------------
__device__ __forceinline__ void ct_dft_stages(const float2* xs, const float2* tts,
                                              float2* S, int t,
                                              float2* out1, float2* out2, int* kout) {
    if (t < 250) {
        int d = t / 25;
        int b = t % 25;
        float2 st = tts[(25 * d) % NN];
        float wr = 1.f, wi = 0.f;
        float Er = 0.f, Ei = 0.f, Or_ = 0.f, Oi = 0.f;
#pragma unroll
        for (int a = 0; a < 20; a += 2) {
            float2 x0 = xs[25 * a + b];
            Er += x0.x * wr - x0.y * wi;
            Ei += x0.x * wi + x0.y * wr;
            float nr = wr * st.x - wi * st.y;
            float ni = wr * st.y + wi * st.x;
            float2 x1 = xs[25 * (a + 1) + b];
            Or_ += x1.x * nr - x1.y * ni;
            Oi  += x1.x * ni + x1.y * nr;
            wr = nr * st.x - ni * st.y;
            wi = nr * st.y + ni * st.x;
        }
        S[b * 21 + d]      = make_float2(Er + Or_, Ei + Oi);
        S[b * 21 + d + 10] = make_float2(Er - Or_, Ei - Oi);
    }
    __syncthreads();
    if (t < 250) {
        int k = t;
        int d1 = k % 20;
        int d2 = (d1 + 10) % 20;
        float2 s1 = tts[k];
        float wr = 1.f, wi = 0.f;
        float a1r = 0.f, a1i = 0.f, a2r = 0.f, a2i = 0.f;
#pragma unroll
        for (int b = 0; b < 25; ++b) {
            float2 u1 = S[b * 21 + d1];
            float2 u2 = S[b * 21 + d2];
            a1r += u1.x * wr - u1.y * wi;
            a1i += u1.x * wi + u1.y * wr;
            float sgnb = (b & 1) ? -1.f : 1.f;
            float w2r = sgnb * wr, w2i = sgnb * wi;
            a2r += u2.x * w2r - u2.y * w2i;
            a2i += u2.x * w2i + u2.y * w2r;
            float nr = wr * s1.x - wi * s1.y;
            wi = wr * s1.y + wi * s1.x;
            wr = nr;
        }
        *out1 = make_float2(a1r, a1i);
        *out2 = make_float2(a2r, a2i);
        *kout = k;
    }
}

// k_dft_rows: fused pupil-field generation (f32) + row DFT; writes R1T[k][y].
__global__ void k_dft_rows(const float* __restrict__ phase, float2* __restrict__ dst,
                           const float2* __restrict__ tw) {
    __shared__ __align__(16) float2 xs[NN];
    __shared__ float2 tts[NN];
    __shared__ float2 S[25 * 21];
    int line = blockIdx.x;                 // y index i
    int t = threadIdx.x;
    const float INV2SIG = 2.2222222e7f;              // 1/(2*(1.5e-4)^2)
    const float C1M = (float)(M_PI / 5.32e-8);       // pi/(WL*FL)
    float y = (float)(line - 250) * 1e-6f;
    float y2 = y * y;
    const float* prow = phase + (size_t)line * NN;
    for (int n = t; n < NN; n += 256) {
        float x = (float)(n - 250) * 1e-6f;
        float r2 = x * x + y2;
        float inc = __expf(-r2 * INV2SIG);
        float c1 = C1M * r2;
        float b1r = __cosf(c1), b1i = -__sinf(c1);
        float ph = prow[n];
        float sp = __sinf(ph), cp = __cosf(ph);
        float ar = inc * cp, ai = inc * sp;
        xs[n] = make_float2(ar * b1r - ai * b1i, ar * b1i + ai * b1r);
        float2 tt = tw[n];
        tts[n] = make_float2(tt.x, -tt.y);   // forward
    }
    __syncthreads();
    float2 o1, o2; int k;
    ct_dft_stages(xs, tts, S, t, &o1, &o2, &k);
    if (t < 250) {
        dst[(size_t)k * NN + line] = o1;           // R1T[k][y]
        dst[(size_t)(k + 250) * NN + line] = o2;
    }
}

__global__ void k_dft_cols(const float2* __restrict__ src, float2* __restrict__ dst,
                           const float2* __restrict__ tw) {
    __shared__ __align__(16) float2 xs[NN];
    __shared__ float2 tts[NN];
    __shared__ float2 S[25 * 21];
    int line = blockIdx.x;                 // kx
    const float2* s = src + (size_t)line * NN;     // R1T row kx, contiguous
    int t = threadIdx.x;
    for (int n = t; n < NN; n += 256) {
        xs[n] = s[n];
        float2 tt = tw[n];
        tts[n] = make_float2(tt.x, -tt.y);
    }
    __syncthreads();
    float2 o1, o2; int k;
    ct_dft_stages(xs, tts, S, t, &o1, &o2, &k);
    if (t < 250) {
        float2* dp = dst + (size_t)line * NN;      // EfT[kx][*], contiguous
        dp[k] = o1;
        dp[k + 250] = o2;
    }
}

// ---------------------------------------------------------------------------
// k_prop_mfma v5: ONE block per v (grid 500, all co-resident at 3 blocks/CU),
// 32x32x16 f16 MFMA (2x MACs per LDS byte vs 16x16x32). 4 waves: waves {0,1}
// compute K-half 0 (kappa 0..511), waves {2,3} K-half 1; per wave 32 z x 64
// nu. The two K-half partial sums are merged IN LDS at the end -> part is a
// single [z][v][64] buffer (8.2 MB) written with float4 stores where 16
// consecutive lanes fully cover one 256-B region (write amplification 1.0;
// v4's interleaved 64-B segment stores caused 5.8x = 94.5 MB WRITE_SIZE).
// B single-buffered per half (43 KB LDS total), T14 reg-prefetch (9 float4)
// across the barrier pair.
//   A[z][2u+p] = {Re,Im}( EfT[v][u]*ASCALE * e^{i kg[v][u] z_z} )
// A-frag 32x32x16: row = lane&31 (z = mw*32+row), k = (lane>>5)*8 + e.
// B-frag: col = lane&31 (nu = nt*32+col), k same.
// C layout (m74/m101-verified): col = lane&31, row = (reg&3)+8*(reg>>2)+4*(lane>>5).
// ---------------------------------------------------------------------------
__global__ void __launch_bounds__(256, 3)
k_prop_mfma(const float2* __restrict__ EfT,
            const float* __restrict__ kgamma,
            const float* __restrict__ zs,
            const _Float16* __restrict__ Bg,
            float* __restrict__ part) {
    // 43008 B: Bbuf [2 halves][9216 f16] (36864) + eft [512]f2 (4096) + kgs [512]f (2048)
    __shared__ __align__(16) char smem[2 * BG_CHUNK * 2 + 512 * 8 + 512 * 4];
    _Float16* Bbuf = (_Float16*)smem;                        // [2][BG_CHUNK]
    float2*   eft  = (float2*)(smem + 2 * BG_CHUNK * 2);     // [512] (u global)
    float*    kgs  = (float*)(smem + 2 * BG_CHUNK * 2 + 512 * 8);
    float*    ctile = (float*)smem;                          // epilogue overlay 64x64 f32

    int v = blockIdx.x;
    int t = threadIdx.x;
    int w = t >> 6;                  // wave 0..3
    int wh = w >> 1;                 // K-half 0/1
    int mw = w & 1;                  // z-block: rows 32*mw..32*mw+31
    int lane = t & 63;
    int l31 = lane & 31;
    int lk = lane >> 5;              // k-oct selector 0/1

    for (int n = t; n < 512; n += 256) {
        if (n < NN) {
            float2 e = EfT[(size_t)v * NN + n];
            eft[n] = make_float2(e.x * ASCALE, e.y * ASCALE);  // fold ASCALE
            kgs[n] = kgamma[(size_t)v * NN + n];
        } else {
            eft[n] = make_float2(0.f, 0.f);
            kgs[n] = 0.f;
        }
    }
    {   // stage chunk 0 for both halves: 2 x 18432 B = 2304 float4
        for (int k = 0; k < 9; ++k) {
            int i = t + k * 256;
            int whs = i / 1152, off = i % 1152;
            ((float4*)Bbuf)[i] =
                ((const float4*)(Bg + (size_t)(8 * whs) * BG_CHUNK))[off];
        }
    }
    float zv = zs[mw * 32 + l31];    // z of this lane's A rows
    __syncthreads();

    f32x16 acc[2] = {};              // 2 n-tiles (nu = nt*32 + l31)

#define MODSPLIT(ex, ey, kgv, i0) do {                                        \
        float s_, c_;                                                         \
        fast_sincos_red((kgv) * zv, &s_, &c_);                                \
        float yr = (ex) * c_ - (ey) * s_;                                     \
        float yi = (ex) * s_ + (ey) * c_;                                     \
        _Float16 h0 = (_Float16)yr;                                           \
        ah[i0] = h0; al[i0] = (_Float16)(yr - (float)h0);                     \
        _Float16 h1 = (_Float16)yi;                                           \
        ah[i0 + 1] = h1; al[i0 + 1] = (_Float16)(yi - (float)h1);             \
    } while (0)

    const _Float16* Bb = Bbuf + wh * BG_CHUNK;
    for (int ci = 0; ci < 8; ++ci) {
        // T14: issue next chunk's global loads early (held in regs past compute)
        float4 stg[9];
        if (ci + 1 < 8) {
#pragma unroll
            for (int k = 0; k < 9; ++k) {
                int i = t + k * 256;
                int whs = i / 1152, off = i % 1152;
                stg[k] = ((const float4*)(Bg +
                            (size_t)(8 * whs + ci + 1) * BG_CHUNK))[off];
            }
        }
#pragma unroll
        for (int sl = 0; sl < 4; ++sl) {
            int step = ci * 4 + sl;              // K16-step 0..31 within half
            int u0 = wh * 256 + step * 8 + lk * 4;   // this lane's 4 u's (broadcast)
            f16x8 ah, al;
            {
                float4 e01 = *(const float4*)&eft[u0];
                float4 e23 = *(const float4*)&eft[u0 + 2];
                float4 kg4 = *(const float4*)&kgs[u0];
                MODSPLIT(e01.x, e01.y, kg4.x, 0);
                MODSPLIT(e01.z, e01.w, kg4.y, 2);
                MODSPLIT(e23.x, e23.y, kg4.z, 4);
                MODSPLIT(e23.z, e23.w, kg4.w, 6);
            }
            int koff = sl * 16 + lk * 8;         // kappa-local within chunk
#pragma unroll
            for (int nt = 0; nt < 2; ++nt) {
                int nu = nt * 32 + l31;
                f16x8 bh = *(const f16x8*)&Bb[nu * BSTR + koff];
                f16x8 bl = *(const f16x8*)&Bb[64 * BSTR + nu * BSTR + koff];
                acc[nt] = __builtin_amdgcn_mfma_f32_32x32x16_f16(ah, bh, acc[nt], 0, 0, 0);
                acc[nt] = __builtin_amdgcn_mfma_f32_32x32x16_f16(al, bh, acc[nt], 0, 0, 0);
                acc[nt] = __builtin_amdgcn_mfma_f32_32x32x16_f16(ah, bl, acc[nt], 0, 0, 0);
            }
        }
        __syncthreads();             // all compute reads of Bbuf done
        if (ci + 1 < 8) {
#pragma unroll
            for (int k = 0; k < 9; ++k) {
                int i = t + k * 256;
                ((float4*)Bbuf)[i] = stg[k];
            }
        }
        __syncthreads();             // staged chunk visible
    }
#undef MODSPLIT

    // ---- merge K-halves in LDS (ctile overlays Bbuf; compute is done) ----
    if (wh == 0) {
#pragma unroll
        for (int nt = 0; nt < 2; ++nt)
#pragma unroll
            for (int reg = 0; reg < 16; ++reg) {
                int row = (reg & 3) + 8 * (reg >> 2) + 4 * lk;
                ctile[(mw * 32 + row) * 64 + nt * 32 + l31] = acc[nt][reg];
            }
    }
    __syncthreads();
    if (wh == 1) {
#pragma unroll
        for (int nt = 0; nt < 2; ++nt)
#pragma unroll
            for (int reg = 0; reg < 16; ++reg) {
                int row = (reg & 3) + 8 * (reg >> 2) + 4 * lk;
                ctile[(mw * 32 + row) * 64 + nt * 32 + l31] += acc[nt][reg];
            }
    }
    __syncthreads();
    // ---- write out: 16 consecutive lanes cover one full 256-B z-region ----
#pragma unroll
    for (int p = 0; p < 4; ++p) {
        int idx = p * 256 + t;        // 0..1023
        int z = idx >> 4, c4 = idx & 15;
        float4 val = *(const float4*)&ctile[z * 64 + c4 * 4];
        *(float4*)&part[((size_t)z * NN + v) * 64 + c4 * 4] = val;
    }
}

// ---------------------------------------------------------------------------
// B2: grid (4 line-groups, 64 z). Block (rq,z) handles ri in [8rq, 8rq+8)
// (rq=3: 7 useful). Per v it reads the one 64B line of part[z][v][16rq..+16)
// (coalesced; fetch == part size). Compute: 8 ri x 31 ci threads, 500-v
// twiddle recurrence re-seeded every 125 steps. inv carries the 1/64 A-scale
// compensation from k_prop_mfma.
// ---------------------------------------------------------------------------
__global__ void k_prop_cols(const float* __restrict__ part,
                            float* __restrict__ psf,
                            float* __restrict__ psf_sums) {
    __shared__ __align__(16) float X2[NN][16];   // 32000 B
    int rq = blockIdx.x;   // 0..3
    int z  = blockIdx.y;   // 0..63
    int t  = threadIdx.x;
    const float* p0 = part + ((size_t)z * NN) * 64 + rq * 16;
    for (int i = t; i < NN * 4; i += 256) {
        int v = i >> 2, q4 = i & 3;
        float4 a = *(const float4*)(p0 + (size_t)v * 64 + q4 * 4);
        *(float4*)&X2[v][q4 * 4] = a;
    }
    __syncthreads();
    int ril = t >> 5;            // 0..7
    int ri  = rq * 8 + ril;
    int ci  = t & 31;
    float val = 0.f;
    if (ri < PW && ci < PW) {
        int c = 235 + ci;
        float ar = 0.f, ai = 0.f;
        float sr, si;
        {
            float th = (TWO_PI_F / NN) * (float)(c % NN);
            sincosf(th, &si, &sr);
        }
        for (int vb = 0; vb < 4; ++vb) {       // exact re-seed every 125 steps
            int v0 = vb * 125;
            float wr, wi;
            float th = (TWO_PI_F / NN) * (float)((v0 * c) % NN);
            sincosf(th, &wi, &wr);
            for (int v = v0; v < v0 + 125; ++v) {
                float2 xy = *(const float2*)&X2[v][2 * ril];
                ar += xy.x * wr - xy.y * wi;
                ai += xy.x * wi + xy.y * wr;
                float nwr = wr * sr - wi * si;
                wi = wr * si + wi * sr;
                wr = nwr;
            }
        }
        const float inv = 64.0f / 250000.0f;   // 1/250000 * 64 (A-scale undo)
        float re = ar * inv, im = ai * inv;
        val = re * re + im * im;
        psf[(size_t)z * (PW * PW) + ri * PW + ci] = val;
    }
    // block sum -> psf_sums[z] (one atomic per wave)
#pragma unroll
    for (int m = 1; m < 64; m <<= 1) val += __shfl_xor(val, m);
    if ((t & 63) == 0) atomicAdd(&psf_sums[z], val);
}

// ---------------------------------------------------------------------------
__global__ void k_scatter(const float* __restrict__ psf,
                          const float* __restrict__ psf_sums,
                          const int* __restrict__ xyz,
                          float* __restrict__ canvas) {
    int e = blockIdx.x;
    int b = blockIdx.y;
    int r0 = xyz[(b * NE + e) * 2 + 0] - RR;
    int c0 = xyz[(b * NE + e) * 2 + 1] - RR;
    float sc = 1.0e6f / (psf_sums[e] + 1e-12f);
    float* cb = canvas + (size_t)b * (CAN * CAN);
    for (int p = threadIdx.x; p < PW * PW; p += blockDim.x) {
        int i = p / PW, j = p % PW;
        atomicAdd(cb + (r0 + i) * CAN + (c0 + j), psf[e * PW * PW + p] * sc);
    }
}

// ---------------------------------------------------------------------------
__global__ void k_final(const float* __restrict__ canvas,
                        const float* __restrict__ kern,
                        const float* __restrict__ eps_dark,
                        const float* __restrict__ eps_photon,
                        const float* __restrict__ eps_read,
                        float* __restrict__ out) {
    __shared__ float kk[49];
    __shared__ float tile[14][40];
    int b = blockIdx.z;
    int tx = threadIdx.x, ty = threadIdx.y;
    int t = ty * 32 + tx;
    int j0 = blockIdx.x * 32, i0 = blockIdx.y * 8;
    if (t < 49) kk[t] = kern[t];
    const float* cb = canvas + (size_t)b * (CAN * CAN);
    for (int p = t; p < 14 * 38; p += 256) {
        int rr = p / 38, cc = p % 38;
        int gi = i0 + rr - 2, gj = j0 + cc - 2;
        tile[rr][cc] = (gi >= 0 && gi < CAN && gj >= 0 && gj < CAN)
                           ? cb[gi * CAN + gj] : 0.f;
    }
    __syncthreads();
    int i = i0 + ty, j = j0 + tx;
    if (i >= OHW || j >= OHW) return;
    float acc = 0.f;
#pragma unroll
    for (int a = 0; a < 7; ++a)
#pragma unroll
        for (int q = 0; q < 7; ++q)
            acc += tile[ty + a][tx + q] * kk[a * 7 + q];
    int idx = b * (OHW * OHW) + i * OHW + j;
    float sig = acc * 0.9f;
    float dark = 0.005f + eps_dark[idx] * sqrtf(0.005f);
    float total = fmaxf(sig + dark, 0.0f);
    float noisy = total + eps_photon[idx] * sqrtf(fmaxf(total, 1e-12f));
    float elec = noisy + eps_read[idx] * 1.6f;
    float adu = fminf(fmaxf(elec * 2.0f, 0.0f), 65535.0f);
    float v = (adu <= 10.0f) ? 1.0f : fminf(adu, 4.0e9f);
    out[idx] = v / 4.0e9f;
}

// ---------------------------------------------------------------------------
extern "C" void kernel_launch(void* const* d_in, const int* in_sizes, int n_in,
                              void* d_out, int out_size, void* d_ws, size_t ws_size,
                              hipStream_t stream) {
    const float* phase    = (const float*)d_in[0];
    const float* zs       = (const float*)d_in[1];
    const int*   xyz      = (const int*)d_in[2];
    const float* std_u    = (const float*)d_in[3];
    const float* epsd     = (const float*)d_in[4];
    const float* epsp     = (const float*)d_in[5];
    const float* epsr     = (const float*)d_in[6];
    float* out = (float*)d_out;

    char* ws = (char*)d_ws;
    size_t off = 0;
    auto alloc = [&](size_t bytes) {
        off = (off + 255) & ~(size_t)255;
        size_t o = off; off += bytes; return o;
    };
    float*  kgamma   = (float*) (ws + alloc((size_t)NN * NN * 4));
    float2* tw       = (float2*)(ws + alloc((size_t)NN * 8));
    float2* R1T      = (float2*)(ws + alloc((size_t)NN * NN * 8));
    float2* EfT      = (float2*)(ws + alloc((size_t)NN * NN * 8));
    float*  part     = (float*) (ws + alloc((size_t)NE * NN * 64 * 4));  // 8.2 MB
    float*  psf      = (float*) (ws + alloc((size_t)NE * PW * PW * 4));
    float*  psf_sums = (float*) (ws + alloc((size_t)NE * 4));
    float*  kern     = (float*) (ws + alloc((size_t)64 * 4));
    float*  canvas   = (float*) (ws + alloc((size_t)BATCH * CAN * CAN * 4));
    _Float16* Bg     = (_Float16*)(ws + alloc((size_t)BCH * BG_CHUNK * 2));
    (void)ws_size; (void)n_in; (void)in_sizes; (void)out_size;

    // grid covers max(NN*NN, SETUP_N) = SETUP_N = 320113 (incl. fused Bg gen)
    k_setup<<<(SETUP_N + 255) / 256, 256, 0, stream>>>(
        std_u, kgamma, tw, kern, canvas, psf_sums, Bg);
    // fft2: rows (fused field gen, writes transposed) then cols (contiguous)
    k_dft_rows<<<NN, 256, 0, stream>>>(phase, R1T, tw);
    k_dft_cols<<<NN, 256, 0, stream>>>(R1T, EfT, tw);
    // partial inverse transforms: one block per v, both K-halves, 32x32 MFMA
    k_prop_mfma<<<NN, 256, 0, stream>>>(EfT, kgamma, zs, Bg, part);
    k_prop_cols<<<dim3(4, NE), 256, 0, stream>>>(part, psf, psf_sums);
    k_scatter<<<dim3(NE, BATCH), 256, 0, stream>>>(psf, psf_sums, xyz, canvas);
    k_final<<<dim3((OHW + 31) / 32, (OHW + 7) / 8, BATCH), dim3(32, 8), 0, stream>>>(
        canvas, kern, epsd, epsp, epsr, out);
}

// Round 6
// 137.380 us; speedup vs baseline: 1.1950x; 1.1950x over previous
//
#include <hip/hip_runtime.h>
#include <math.h>

#define NN 500
#define NE 64
#define BATCH 8
#define RR 15
#define PW 31            // 2R+1
#define CAN 200
#define OHW 198
#define TWO_PI_F 6.28318530717958647692f
// k_setup must cover canvas (320000) + psf_sums (64) + kern (49) AND NN*NN.
#define SETUP_N (BATCH * CAN * CAN + NE + 49)

// --- MFMA prop-rows parameters ---------------------------------------------
// kappa = 2u + p (p=0 re, p=1 im), u padded 500->512 => K = 1024 = 64 K16-steps
// Bg2: B fragments PRE-SWIZZLED in per-lane order for mfma_f32_32x32x16_f16:
//   [gs=0..63][plane hi/lo][nt 0..1][lane 0..63][e 0..7] f16   (256 KB)
//   kappa = gs*16 + (lane>>5)*8 + e ;  nu = nt*32 + (lane&31)
// A wave's fragment load = global_load_dwordx4 of 64 lanes x 16 B contiguous.
#define BG2_F16 (64 * 2 * 2 * 64 * 8)   // 131072 f16 = 256 KB
#define ASCALE (1.0f / 64.0f)      // A pre-scale (f16 range safety); undone in k_prop_cols
// part: [z][v][64 nu] floats — nu fastest, 62 useful + 2 pad = 256 B region

using f16x8 = __attribute__((ext_vector_type(8))) _Float16;
using f32x16 = __attribute__((ext_vector_type(16))) float;

// Fast accurate sincos for |theta| up to ~1200 rad: Cody-Waite 2-term
// reduction + hardware v_sin/v_cos on the reduced |r| <= pi argument.
__device__ __forceinline__ void fast_sincos_red(float theta, float* s, float* c) {
    const float INV2PI = 0.15915494309189535f;
    const float PI2_HI = 6.28318548202514648f;   // f32(2*pi)
    const float PI2_LO = -1.7484556e-7f;         // 2*pi - PI2_HI
    float n = rintf(theta * INV2PI);
    float r = fmaf(n, -PI2_HI, theta);
    r = fmaf(n, -PI2_LO, r);
    *s = __sinf(r);
    *c = __cosf(r);
}

// ---------------------------------------------------------------------------
// K_setup: K*GAMMA table (f64 sqrt path), 500-pt twiddle table, blur-kernel
// coefficients, canvas+psf_sums zero, AND the fragment-order f16 hi/lo
// twiddle matrix Bg2 for the MFMA partial-IDFT:
//   B[kappa][nu]: kappa = 2u+p, nu = 2*(r-235)+q (q=0 re-col, q=1 im-col)
//     q=0: p=0 ->  W.re   p=1 -> -W.im
//     q=1: p=0 ->  W.im   p=1 ->  W.re        (W = e^{+2pi i u r / 500})
// GRID MUST COVER SETUP_N.
// ---------------------------------------------------------------------------
__global__ void k_setup(const float* __restrict__ std_u,
                        float* __restrict__ kgamma,
                        float2* __restrict__ tw,
                        float* __restrict__ kern,
                        float* __restrict__ canvas,
                        float* __restrict__ psf_sums,
                        _Float16* __restrict__ Bg2) {
    int idx = blockIdx.x * blockDim.x + threadIdx.x;
    if (idx < NN) {
        double th = 2.0 * M_PI * (double)idx / (double)NN;
        tw[idx] = make_float2((float)cos(th), (float)sin(th));
    }
    if (idx < BG2_F16) {   // fragment-order Bg2 generation
        int e = idx & 7;
        int lane = (idx >> 3) & 63;
        int nt = (idx >> 9) & 1;
        int plane = (idx >> 10) & 1;
        int gs = idx >> 11;            // 0..63
        int kap = gs * 16 + (lane >> 5) * 8 + e;
        int nu = nt * 32 + (lane & 31);
        float outv = 0.f;
        if (kap < 2 * NN) {
            int u = kap >> 1, p = kap & 1;
            int ri = nu >> 1, q = nu & 1;
            int r = 235 + ri;          // ri=31 -> dummy col pair (never read)
            int m = (u * r) % NN;
            double th = 2.0 * M_PI * (double)m / (double)NN;
            double wre = cos(th), wim = sin(th);
            double val = (q == 0) ? ((p == 0) ? wre : -wim)
                                  : ((p == 0) ? wim : wre);
            float x = (float)val;
            _Float16 h = (_Float16)x;
            outv = (plane == 0) ? (float)h : (x - (float)h);
        }
        Bg2[idx] = (_Float16)outv;
    }
    if (idx < BATCH * CAN * CAN) canvas[idx] = 0.f;
    if (idx >= BATCH * CAN * CAN && idx < BATCH * CAN * CAN + NE)
        psf_sums[idx - BATCH * CAN * CAN] = 0.f;
    if (idx >= BATCH * CAN * CAN + NE && idx < SETUP_N) {
        int t = idx - (BATCH * CAN * CAN + NE);
        float stdv = 0.8f + 0.4f * std_u[0];
        float s2 = stdv * stdv;
        int a = t / 7 - 3, b = t % 7 - 3;
        float g = (float)exp(-0.5 * (double)(a * a + b * b));
        kern[t] = (1.0f / (2.0f * (float)M_PI * s2)) * powf(g, 1.0f / s2);
    }
    if (idx >= NN * NN) return;
    int i = idx / NN, j = idx % NN;
    double fy = (double)((i < 250) ? i : i - 500) * 2000.0;
    double fx = (double)((j < 250) ? j : j - 500) * 2000.0;
    double a = 5.32e-7 * fx;
    double b = 5.32e-7 * fy;
    double g = 1.0 - a * a - b * b;
    g = (g > 0.0) ? sqrt(g) : 0.0;
    float Kf = (float)(2.0 * M_PI * 1.0 / 5.32e-7);
    kgamma[idx] = Kf * (float)g;
}

// ---------------------------------------------------------------------------
// 500-pt forward DFT via Cooley-Tukey 20x25. Shared stages helper.
// ---------------------------------------------------------------------------
__device__ __forceinline__ void ct_dft_stages(const float2* xs, const float2* tts,
                                              float2* S, int t,
                                              float2* out1, float2* out2, int* kout) {
    if (t < 250) {
        int d = t / 25;
        int b = t % 25;
        float2 st = tts[(25 * d) % NN];
        float wr = 1.f, wi = 0.f;
        float Er = 0.f, Ei = 0.f, Or_ = 0.f, Oi = 0.f;
#pragma unroll
        for (int a = 0; a < 20; a += 2) {
            float2 x0 = xs[25 * a + b];
            Er += x0.x * wr - x0.y * wi;
            Ei += x0.x * wi + x0.y * wr;
            float nr = wr * st.x - wi * st.y;
            float ni = wr * st.y + wi * st.x;
            float2 x1 = xs[25 * (a + 1) + b];
            Or_ += x1.x * nr - x1.y * ni;
            Oi  += x1.x * ni + x1.y * nr;
            wr = nr * st.x - ni * st.y;
            wi = nr * st.y + ni * st.x;
        }
        S[b * 21 + d]      = make_float2(Er + Or_, Ei + Oi);
        S[b * 21 + d + 10] = make_float2(Er - Or_, Ei - Oi);
    }
    __syncthreads();
    if (t < 250) {
        int k = t;
        int d1 = k % 20;
        int d2 = (d1 + 10) % 20;
        float2 s1 = tts[k];
        float wr = 1.f, wi = 0.f;
        float a1r = 0.f, a1i = 0.f, a2r = 0.f, a2i = 0.f;
#pragma unroll
        for (int b = 0; b < 25; ++b) {
            float2 u1 = S[b * 21 + d1];
            float2 u2 = S[b * 21 + d2];
            a1r += u1.x * wr - u1.y * wi;
            a1i += u1.x * wi + u1.y * wr;
            float sgnb = (b & 1) ? -1.f : 1.f;
            float w2r = sgnb * wr, w2i = sgnb * wi;
            a2r += u2.x * w2r - u2.y * w2i;
            a2i += u2.x * w2i + u2.y * w2r;
            float nr = wr * s1.x - wi * s1.y;
            wi = wr * s1.y + wi * s1.x;
            wr = nr;
        }
        *out1 = make_float2(a1r, a1i);
        *out2 = make_float2(a2r, a2i);
        *kout = k;
    }
}

// k_dft_rows: fused pupil-field generation (f32) + row DFT; writes R1T[k][y].
__global__ void k_dft_rows(const float* __restrict__ phase, float2* __restrict__ dst,
                           const float2* __restrict__ tw) {
    __shared__ __align__(16) float2 xs[NN];
    __shared__ float2 tts[NN];
    __shared__ float2 S[25 * 21];
    int line = blockIdx.x;                 // y index i
    int t = threadIdx.x;
    const float INV2SIG = 2.2222222e7f;              // 1/(2*(1.5e-4)^2)
    const float C1M = (float)(M_PI / 5.32e-8);       // pi/(WL*FL)
    float y = (float)(line - 250) * 1e-6f;
    float y2 = y * y;
    const float* prow = phase + (size_t)line * NN;
    for (int n = t; n < NN; n += 256) {
        float x = (float)(n - 250) * 1e-6f;
        float r2 = x * x + y2;
        float inc = __expf(-r2 * INV2SIG);
        float c1 = C1M * r2;
        float b1r = __cosf(c1), b1i = -__sinf(c1);
        float ph = prow[n];
        float sp = __sinf(ph), cp = __cosf(ph);
        float ar = inc * cp, ai = inc * sp;
        xs[n] = make_float2(ar * b1r - ai * b1i, ar * b1i + ai * b1r);
        float2 tt = tw[n];
        tts[n] = make_float2(tt.x, -tt.y);   // forward
    }
    __syncthreads();
    float2 o1, o2; int k;
    ct_dft_stages(xs, tts, S, t, &o1, &o2, &k);
    if (t < 250) {
        dst[(size_t)k * NN + line] = o1;           // R1T[k][y]
        dst[(size_t)(k + 250) * NN + line] = o2;
    }
}

__global__ void k_dft_cols(const float2* __restrict__ src, float2* __restrict__ dst,
                           const float2* __restrict__ tw) {
    __shared__ __align__(16) float2 xs[NN];
    __shared__ float2 tts[NN];
    __shared__ float2 S[25 * 21];
    int line = blockIdx.x;                 // kx
    const float2* s = src + (size_t)line * NN;     // R1T row kx, contiguous
    int t = threadIdx.x;
    for (int n = t; n < NN; n += 256) {
        xs[n] = s[n];
        float2 tt = tw[n];
        tts[n] = make_float2(tt.x, -tt.y);
    }
    __syncthreads();
    float2 o1, o2; int k;
    ct_dft_stages(xs, tts, S, t, &o1, &o2, &k);
    if (t < 250) {
        float2* dp = dst + (size_t)line * NN;      // EfT[kx][*], contiguous
        dp[k] = o1;
        dp[k + 250] = o2;
    }
}

// ---------------------------------------------------------------------------
// k_prop_mfma v6: NO LDS STAGING OF B, NO MAIN-LOOP BARRIERS. One block per v
// (grid 500), 4 independent waves: wave (mw = z-half, wh = K-half). Each wave
// streams its B fragments DIRECTLY from the pre-swizzled Bg2 (L2-resident,
// 256 KB): per K16-step, 4 coalesced global_load_dwordx4 (64 lanes x 16 B
// contiguous each) + 3 broadcast LDS reads (eft/kgs) + modulation VALU +
// 6 MFMA. Barrier-free loop -> compiler software-pipelines loads (unroll 4,
// ~16 outstanding). v5's barrier-lockstep staging (2 barriers x 8 chunks +
// 9 in-flight float4 regs) was the stall; all of it is gone.
//   A[z][2u+p] = {Re,Im}( EfT[v][u]*ASCALE * e^{i kg[v][u] z_z} )
// A-frag 32x32x16 (v5-verified): row = lane&31 (z = mw*32+row), k = lk*8+e.
// C layout (m74/m101-verified): col = lane&31, row = (reg&3)+8*(reg>>2)+4*lk.
// K-halves merged in LDS ctile; full-line float4 stores to part[z][v][64].
// ---------------------------------------------------------------------------
__global__ void __launch_bounds__(256)
k_prop_mfma(const float2* __restrict__ EfT,
            const float* __restrict__ kgamma,
            const float* __restrict__ zs,
            const _Float16* __restrict__ Bg2,
            float* __restrict__ part) {
    __shared__ __align__(16) float2 eft[512];        // 4096 B
    __shared__ __align__(16) float kgs[512];         // 2048 B
    __shared__ __align__(16) float ctile[64 * 64];   // 16384 B (total 22528)

    int v = blockIdx.x;
    int t = threadIdx.x;
    int w = t >> 6;                  // wave 0..3
    int wh = w >> 1;                 // K-half 0/1 (kappa 512*wh ..)
    int mw = w & 1;                  // z-half: rows 32*mw..32*mw+31
    int lane = t & 63;
    int l31 = lane & 31;
    int lk = lane >> 5;              // k-oct selector 0/1

    for (int n = t; n < 512; n += 256) {
        if (n < NN) {
            float2 e = EfT[(size_t)v * NN + n];
            eft[n] = make_float2(e.x * ASCALE, e.y * ASCALE);  // fold ASCALE
            kgs[n] = kgamma[(size_t)v * NN + n];
        } else {
            eft[n] = make_float2(0.f, 0.f);
            kgs[n] = 0.f;
        }
    }
    float zv = zs[mw * 32 + l31];    // z of this lane's A rows
    __syncthreads();                 // eft/kgs ready; no further compute barriers

    f32x16 acc[2] = {};              // 2 n-tiles (nu = nt*32 + l31)

#define MODSPLIT(ex, ey, kgv, i0) do {                                        \
        float s_, c_;                                                         \
        fast_sincos_red((kgv) * zv, &s_, &c_);                                \
        float yr = (ex) * c_ - (ey) * s_;                                     \
        float yi = (ex) * s_ + (ey) * c_;                                     \
        _Float16 h0 = (_Float16)yr;                                           \
        ah[i0] = h0; al[i0] = (_Float16)(yr - (float)h0);                     \
        _Float16 h1 = (_Float16)yi;                                           \
        ah[i0 + 1] = h1; al[i0 + 1] = (_Float16)(yi - (float)h1);             \
    } while (0)

    // per global K16-step gs = wh*32 + s: fragment group at Bg2 + gs*2048,
    // layout {bh0, bh1, bl0, bl1} x [lane][8]
    const _Float16* bbase = Bg2 + (size_t)(wh * 32) * 2048 + (size_t)lane * 8;
#pragma unroll 4
    for (int s = 0; s < 32; ++s) {
        const _Float16* bs = bbase + (size_t)s * 2048;
        f16x8 bh0 = *(const f16x8*)(bs);
        f16x8 bh1 = *(const f16x8*)(bs + 512);
        f16x8 bl0 = *(const f16x8*)(bs + 1024);
        f16x8 bl1 = *(const f16x8*)(bs + 1536);
        int u0 = wh * 256 + s * 8 + lk * 4;      // this lane's 4 u's (broadcast)
        f16x8 ah, al;
        {
            float4 e01 = *(const float4*)&eft[u0];
            float4 e23 = *(const float4*)&eft[u0 + 2];
            float4 kg4 = *(const float4*)&kgs[u0];
            MODSPLIT(e01.x, e01.y, kg4.x, 0);
            MODSPLIT(e01.z, e01.w, kg4.y, 2);
            MODSPLIT(e23.x, e23.y, kg4.z, 4);
            MODSPLIT(e23.z, e23.w, kg4.w, 6);
        }
        acc[0] = __builtin_amdgcn_mfma_f32_32x32x16_f16(ah, bh0, acc[0], 0, 0, 0);
        acc[0] = __builtin_amdgcn_mfma_f32_32x32x16_f16(al, bh0, acc[0], 0, 0, 0);
        acc[0] = __builtin_amdgcn_mfma_f32_32x32x16_f16(ah, bl0, acc[0], 0, 0, 0);
        acc[1] = __builtin_amdgcn_mfma_f32_32x32x16_f16(ah, bh1, acc[1], 0, 0, 0);
        acc[1] = __builtin_amdgcn_mfma_f32_32x32x16_f16(al, bh1, acc[1], 0, 0, 0);
        acc[1] = __builtin_amdgcn_mfma_f32_32x32x16_f16(ah, bl1, acc[1], 0, 0, 0);
    }
#undef MODSPLIT

    // ---- merge K-halves in LDS ----
    if (wh == 0) {
#pragma unroll
        for (int nt = 0; nt < 2; ++nt)
#pragma unroll
            for (int reg = 0; reg < 16; ++reg) {
                int row = (reg & 3) + 8 * (reg >> 2) + 4 * lk;
                ctile[(mw * 32 + row) * 64 + nt * 32 + l31] = acc[nt][reg];
            }
    }
    __syncthreads();
    if (wh == 1) {
#pragma unroll
        for (int nt = 0; nt < 2; ++nt)
#pragma unroll
            for (int reg = 0; reg < 16; ++reg) {
                int row = (reg & 3) + 8 * (reg >> 2) + 4 * lk;
                ctile[(mw * 32 + row) * 64 + nt * 32 + l31] += acc[nt][reg];
            }
    }
    __syncthreads();
    // ---- write out: 16 consecutive lanes cover one full 256-B z-region ----
#pragma unroll
    for (int p = 0; p < 4; ++p) {
        int idx = p * 256 + t;        // 0..1023
        int z = idx >> 4, c4 = idx & 15;
        float4 val = *(const float4*)&ctile[z * 64 + c4 * 4];
        *(float4*)&part[((size_t)z * NN + v) * 64 + c4 * 4] = val;
    }
}

// ---------------------------------------------------------------------------
// B2: grid (4 line-groups, 64 z). Block (rq,z) handles ri in [8rq, 8rq+8)
// (rq=3: 7 useful). Per v it reads the one 64B line of part[z][v][16rq..+16)
// (coalesced; fetch == part size). Compute: 8 ri x 31 ci threads, 500-v
// twiddle recurrence re-seeded every 125 steps. inv carries the 1/64 A-scale
// compensation from k_prop_mfma.
// ---------------------------------------------------------------------------
__global__ void k_prop_cols(const float* __restrict__ part,
                            float* __restrict__ psf,
                            float* __restrict__ psf_sums) {
    __shared__ __align__(16) float X2[NN][16];   // 32000 B
    int rq = blockIdx.x;   // 0..3
    int z  = blockIdx.y;   // 0..63
    int t  = threadIdx.x;
    const float* p0 = part + ((size_t)z * NN) * 64 + rq * 16;
    for (int i = t; i < NN * 4; i += 256) {
        int v = i >> 2, q4 = i & 3;
        float4 a = *(const float4*)(p0 + (size_t)v * 64 + q4 * 4);
        *(float4*)&X2[v][q4 * 4] = a;
    }
    __syncthreads();
    int ril = t >> 5;            // 0..7
    int ri  = rq * 8 + ril;
    int ci  = t & 31;
    float val = 0.f;
    if (ri < PW && ci < PW) {
        int c = 235 + ci;
        float ar = 0.f, ai = 0.f;
        float sr, si;
        {
            float th = (TWO_PI_F / NN) * (float)(c % NN);
            sincosf(th, &si, &sr);
        }
        for (int vb = 0; vb < 4; ++vb) {       // exact re-seed every 125 steps
            int v0 = vb * 125;
            float wr, wi;
            float th = (TWO_PI_F / NN) * (float)((v0 * c) % NN);
            sincosf(th, &wi, &wr);
            for (int v = v0; v < v0 + 125; ++v) {
                float2 xy = *(const float2*)&X2[v][2 * ril];
                ar += xy.x * wr - xy.y * wi;
                ai += xy.x * wi + xy.y * wr;
                float nwr = wr * sr - wi * si;
                wi = wr * si + wi * sr;
                wr = nwr;
            }
        }
        const float inv = 64.0f / 250000.0f;   // 1/250000 * 64 (A-scale undo)
        float re = ar * inv, im = ai * inv;
        val = re * re + im * im;
        psf[(size_t)z * (PW * PW) + ri * PW + ci] = val;
    }
    // block sum -> psf_sums[z] (one atomic per wave)
#pragma unroll
    for (int m = 1; m < 64; m <<= 1) val += __shfl_xor(val, m);
    if ((t & 63) == 0) atomicAdd(&psf_sums[z], val);
}

// ---------------------------------------------------------------------------
__global__ void k_scatter(const float* __restrict__ psf,
                          const float* __restrict__ psf_sums,
                          const int* __restrict__ xyz,
                          float* __restrict__ canvas) {
    int e = blockIdx.x;
    int b = blockIdx.y;
    int r0 = xyz[(b * NE + e) * 2 + 0] - RR;
    int c0 = xyz[(b * NE + e) * 2 + 1] - RR;
    float sc = 1.0e6f / (psf_sums[e] + 1e-12f);
    float* cb = canvas + (size_t)b * (CAN * CAN);
    for (int p = threadIdx.x; p < PW * PW; p += blockDim.x) {
        int i = p / PW, j = p % PW;
        atomicAdd(cb + (r0 + i) * CAN + (c0 + j), psf[e * PW * PW + p] * sc);
    }
}

// ---------------------------------------------------------------------------
__global__ void k_final(const float* __restrict__ canvas,
                        const float* __restrict__ kern,
                        const float* __restrict__ eps_dark,
                        const float* __restrict__ eps_photon,
                        const float* __restrict__ eps_read,
                        float* __restrict__ out) {
    __shared__ float kk[49];
    __shared__ float tile[14][40];
    int b = blockIdx.z;
    int tx = threadIdx.x, ty = threadIdx.y;
    int t = ty * 32 + tx;
    int j0 = blockIdx.x * 32, i0 = blockIdx.y * 8;
    if (t < 49) kk[t] = kern[t];
    const float* cb = canvas + (size_t)b * (CAN * CAN);
    for (int p = t; p < 14 * 38; p += 256) {
        int rr = p / 38, cc = p % 38;
        int gi = i0 + rr - 2, gj = j0 + cc - 2;
        tile[rr][cc] = (gi >= 0 && gi < CAN && gj >= 0 && gj < CAN)
                           ? cb[gi * CAN + gj] : 0.f;
    }
    __syncthreads();
    int i = i0 + ty, j = j0 + tx;
    if (i >= OHW || j >= OHW) return;
    float acc = 0.f;
#pragma unroll
    for (int a = 0; a < 7; ++a)
#pragma unroll
        for (int q = 0; q < 7; ++q)
            acc += tile[ty + a][tx + q] * kk[a * 7 + q];
    int idx = b * (OHW * OHW) + i * OHW + j;
    float sig = acc * 0.9f;
    float dark = 0.005f + eps_dark[idx] * sqrtf(0.005f);
    float total = fmaxf(sig + dark, 0.0f);
    float noisy = total + eps_photon[idx] * sqrtf(fmaxf(total, 1e-12f));
    float elec = noisy + eps_read[idx] * 1.6f;
    float adu = fminf(fmaxf(elec * 2.0f, 0.0f), 65535.0f);
    float v = (adu <= 10.0f) ? 1.0f : fminf(adu, 4.0e9f);
    out[idx] = v / 4.0e9f;
}

// ---------------------------------------------------------------------------
extern "C" void kernel_launch(void* const* d_in, const int* in_sizes, int n_in,
                              void* d_out, int out_size, void* d_ws, size_t ws_size,
                              hipStream_t stream) {
    const float* phase    = (const float*)d_in[0];
    const float* zs       = (const float*)d_in[1];
    const int*   xyz      = (const int*)d_in[2];
    const float* std_u    = (const float*)d_in[3];
    const float* epsd     = (const float*)d_in[4];
    const float* epsp     = (const float*)d_in[5];
    const float* epsr     = (const float*)d_in[6];
    float* out = (float*)d_out;

    char* ws = (char*)d_ws;
    size_t off = 0;
    auto alloc = [&](size_t bytes) {
        off = (off + 255) & ~(size_t)255;
        size_t o = off; off += bytes; return o;
    };
    float*  kgamma   = (float*) (ws + alloc((size_t)NN * NN * 4));
    float2* tw       = (float2*)(ws + alloc((size_t)NN * 8));
    float2* R1T      = (float2*)(ws + alloc((size_t)NN * NN * 8));
    float2* EfT      = (float2*)(ws + alloc((size_t)NN * NN * 8));
    float*  part     = (float*) (ws + alloc((size_t)NE * NN * 64 * 4));  // 8.2 MB
    float*  psf      = (float*) (ws + alloc((size_t)NE * PW * PW * 4));
    float*  psf_sums = (float*) (ws + alloc((size_t)NE * 4));
    float*  kern     = (float*) (ws + alloc((size_t)64 * 4));
    float*  canvas   = (float*) (ws + alloc((size_t)BATCH * CAN * CAN * 4));
    _Float16* Bg2    = (_Float16*)(ws + alloc((size_t)BG2_F16 * 2));     // 256 KB
    (void)ws_size; (void)n_in; (void)in_sizes; (void)out_size;

    // grid covers max(NN*NN, SETUP_N) = SETUP_N = 320113 (incl. Bg2 gen)
    k_setup<<<(SETUP_N + 255) / 256, 256, 0, stream>>>(
        std_u, kgamma, tw, kern, canvas, psf_sums, Bg2);
    // fft2: rows (fused field gen, writes transposed) then cols (contiguous)
    k_dft_rows<<<NN, 256, 0, stream>>>(phase, R1T, tw);
    k_dft_cols<<<NN, 256, 0, stream>>>(R1T, EfT, tw);
    // partial inverse transforms: barrier-free direct-from-L2 B fragments
    k_prop_mfma<<<NN, 256, 0, stream>>>(EfT, kgamma, zs, Bg2, part);
    k_prop_cols<<<dim3(4, NE), 256, 0, stream>>>(part, psf, psf_sums);
    k_scatter<<<dim3(NE, BATCH), 256, 0, stream>>>(psf, psf_sums, xyz, canvas);
    k_final<<<dim3((OHW + 31) / 32, (OHW + 7) / 8, BATCH), dim3(32, 8), 0, stream>>>(
        canvas, kern, epsd, epsp, epsr, out);
}

// Round 7
// 136.357 us; speedup vs baseline: 1.2039x; 1.0075x over previous
//
#include <hip/hip_runtime.h>
#include <math.h>

#define NN 500
#define NE 64
#define BATCH 8
#define RR 15
#define PW 31            // 2R+1
#define CAN 200
#define OHW 198
#define TWO_PI_F 6.28318530717958647692f
// k_setup must cover canvas (320000) + psf_sums (64) + kern (49) AND NN*NN.
#define SETUP_N (BATCH * CAN * CAN + NE + 49)

// --- MFMA prop-rows parameters ---------------------------------------------
// kappa = 2u + p (p=0 re, p=1 im), u padded 500->512 => K = 1024 = 64 K16-steps
// Bg2: B fragments PRE-SWIZZLED in per-lane order for mfma_f32_32x32x16_f16:
//   [gs=0..63][plane hi/lo][nt 0..1][lane 0..63][e 0..7] f16   (256 KB)
//   kappa = gs*16 + (lane>>5)*8 + e ;  nu = nt*32 + (lane&31)
// A wave's fragment load = global_load_dwordx4 of 64 lanes x 16 B contiguous.
#define BG2_F16 (64 * 2 * 2 * 64 * 8)   // 131072 f16 = 256 KB
#define ASCALE (1.0f / 64.0f)      // A pre-scale (f16 range safety); undone in k_prop_cols
// part: [z][v][64 nu] floats — nu fastest, 62 useful + 2 pad = 256 B region

using f16x8 = __attribute__((ext_vector_type(8))) _Float16;
using f32x16 = __attribute__((ext_vector_type(16))) float;

// Fast accurate sincos for |theta| up to ~1200 rad: Cody-Waite 2-term
// reduction + hardware v_sin/v_cos on the reduced |r| <= pi argument.
__device__ __forceinline__ void fast_sincos_red(float theta, float* s, float* c) {
    const float INV2PI = 0.15915494309189535f;
    const float PI2_HI = 6.28318548202514648f;   // f32(2*pi)
    const float PI2_LO = -1.7484556e-7f;         // 2*pi - PI2_HI
    float n = rintf(theta * INV2PI);
    float r = fmaf(n, -PI2_HI, theta);
    r = fmaf(n, -PI2_LO, r);
    *s = __sinf(r);
    *c = __cosf(r);
}

// ---------------------------------------------------------------------------
// K_setup: K*GAMMA table (f64 sqrt path), 500-pt twiddle table, blur-kernel
// coefficients, canvas+psf_sums zero, AND the fragment-order f16 hi/lo
// twiddle matrix Bg2 for the MFMA partial-IDFT:
//   B[kappa][nu]: kappa = 2u+p, nu = 2*(r-235)+q (q=0 re-col, q=1 im-col)
//     q=0: p=0 ->  W.re   p=1 -> -W.im
//     q=1: p=0 ->  W.im   p=1 ->  W.re        (W = e^{+2pi i u r / 500})
// GRID MUST COVER SETUP_N.
// ---------------------------------------------------------------------------
__global__ void k_setup(const float* __restrict__ std_u,
                        float* __restrict__ kgamma,
                        float2* __restrict__ tw,
                        float* __restrict__ kern,
                        float* __restrict__ canvas,
                        float* __restrict__ psf_sums,
                        _Float16* __restrict__ Bg2) {
    int idx = blockIdx.x * blockDim.x + threadIdx.x;
    if (idx < NN) {
        double th = 2.0 * M_PI * (double)idx / (double)NN;
        tw[idx] = make_float2((float)cos(th), (float)sin(th));
    }
    if (idx < BG2_F16) {   // fragment-order Bg2 generation
        int e = idx & 7;
        int lane = (idx >> 3) & 63;
        int nt = (idx >> 9) & 1;
        int plane = (idx >> 10) & 1;
        int gs = idx >> 11;            // 0..63
        int kap = gs * 16 + (lane >> 5) * 8 + e;
        int nu = nt * 32 + (lane & 31);
        float outv = 0.f;
        if (kap < 2 * NN) {
            int u = kap >> 1, p = kap & 1;
            int ri = nu >> 1, q = nu & 1;
            int r = 235 + ri;          // ri=31 -> dummy col pair (never read)
            int m = (u * r) % NN;
            double th = 2.0 * M_PI * (double)m / (double)NN;
            double wre = cos(th), wim = sin(th);
            double val = (q == 0) ? ((p == 0) ? wre : -wim)
                                  : ((p == 0) ? wim : wre);
            float x = (float)val;
            _Float16 h = (_Float16)x;
            outv = (plane == 0) ? (float)h : (x - (float)h);
        }
        Bg2[idx] = (_Float16)outv;
    }
    if (idx < BATCH * CAN * CAN) canvas[idx] = 0.f;
    if (idx >= BATCH * CAN * CAN && idx < BATCH * CAN * CAN + NE)
        psf_sums[idx - BATCH * CAN * CAN] = 0.f;
    if (idx >= BATCH * CAN * CAN + NE && idx < SETUP_N) {
        int t = idx - (BATCH * CAN * CAN + NE);
        float stdv = 0.8f + 0.4f * std_u[0];
        float s2 = stdv * stdv;
        int a = t / 7 - 3, b = t % 7 - 3;
        float g = (float)exp(-0.5 * (double)(a * a + b * b));
        kern[t] = (1.0f / (2.0f * (float)M_PI * s2)) * powf(g, 1.0f / s2);
    }
    if (idx >= NN * NN) return;
    int i = idx / NN, j = idx % NN;
    double fy = (double)((i < 250) ? i : i - 500) * 2000.0;
    double fx = (double)((j < 250) ? j : j - 500) * 2000.0;
    double a = 5.32e-7 * fx;
    double b = 5.32e-7 * fy;
    double g = 1.0 - a * a - b * b;
    g = (g > 0.0) ? sqrt(g) : 0.0;
    float Kf = (float)(2.0 * M_PI * 1.0 / 5.32e-7);
    kgamma[idx] = Kf * (float)g;
}

// ---------------------------------------------------------------------------
// 500-pt forward DFT via Cooley-Tukey 20x25. Shared stages helper.
// ---------------------------------------------------------------------------
__device__ __forceinline__ void ct_dft_stages(const float2* xs, const float2* tts,
                                              float2* S, int t,
                                              float2* out1, float2* out2, int* kout) {
    if (t < 250) {
        int d = t / 25;
        int b = t % 25;
        float2 st = tts[(25 * d) % NN];
        float wr = 1.f, wi = 0.f;
        float Er = 0.f, Ei = 0.f, Or_ = 0.f, Oi = 0.f;
#pragma unroll
        for (int a = 0; a < 20; a += 2) {
            float2 x0 = xs[25 * a + b];
            Er += x0.x * wr - x0.y * wi;
            Ei += x0.x * wi + x0.y * wr;
            float nr = wr * st.x - wi * st.y;
            float ni = wr * st.y + wi * st.x;
            float2 x1 = xs[25 * (a + 1) + b];
            Or_ += x1.x * nr - x1.y * ni;
            Oi  += x1.x * ni + x1.y * nr;
            wr = nr * st.x - ni * st.y;
            wi = nr * st.y + ni * st.x;
        }
        S[b * 21 + d]      = make_float2(Er + Or_, Ei + Oi);
        S[b * 21 + d + 10] = make_float2(Er - Or_, Ei - Oi);
    }
    __syncthreads();
    if (t < 250) {
        int k = t;
        int d1 = k % 20;
        int d2 = (d1 + 10) % 20;
        float2 s1 = tts[k];
        float wr = 1.f, wi = 0.f;
        float a1r = 0.f, a1i = 0.f, a2r = 0.f, a2i = 0.f;
#pragma unroll
        for (int b = 0; b < 25; ++b) {
            float2 u1 = S[b * 21 + d1];
            float2 u2 = S[b * 21 + d2];
            a1r += u1.x * wr - u1.y * wi;
            a1i += u1.x * wi + u1.y * wr;
            float sgnb = (b & 1) ? -1.f : 1.f;
            float w2r = sgnb * wr, w2i = sgnb * wi;
            a2r += u2.x * w2r - u2.y * w2i;
            a2i += u2.x * w2i + u2.y * w2r;
            float nr = wr * s1.x - wi * s1.y;
            wi = wr * s1.y + wi * s1.x;
            wr = nr;
        }
        *out1 = make_float2(a1r, a1i);
        *out2 = make_float2(a2r, a2i);
        *kout = k;
    }
}

// k_dft_rows: fused pupil-field generation (f32) + row DFT; writes R1T[k][y].
__global__ void k_dft_rows(const float* __restrict__ phase, float2* __restrict__ dst,
                           const float2* __restrict__ tw) {
    __shared__ __align__(16) float2 xs[NN];
    __shared__ float2 tts[NN];
    __shared__ float2 S[25 * 21];
    int line = blockIdx.x;                 // y index i
    int t = threadIdx.x;
    const float INV2SIG = 2.2222222e7f;              // 1/(2*(1.5e-4)^2)
    const float C1M = (float)(M_PI / 5.32e-8);       // pi/(WL*FL)
    float y = (float)(line - 250) * 1e-6f;
    float y2 = y * y;
    const float* prow = phase + (size_t)line * NN;
    for (int n = t; n < NN; n += 256) {
        float x = (float)(n - 250) * 1e-6f;
        float r2 = x * x + y2;
        float inc = __expf(-r2 * INV2SIG);
        float c1 = C1M * r2;
        float b1r = __cosf(c1), b1i = -__sinf(c1);
        float ph = prow[n];
        float sp = __sinf(ph), cp = __cosf(ph);
        float ar = inc * cp, ai = inc * sp;
        xs[n] = make_float2(ar * b1r - ai * b1i, ar * b1i + ai * b1r);
        float2 tt = tw[n];
        tts[n] = make_float2(tt.x, -tt.y);   // forward
    }
    __syncthreads();
    float2 o1, o2; int k;
    ct_dft_stages(xs, tts, S, t, &o1, &o2, &k);
    if (t < 250) {
        dst[(size_t)k * NN + line] = o1;           // R1T[k][y]
        dst[(size_t)(k + 250) * NN + line] = o2;
    }
}

__global__ void k_dft_cols(const float2* __restrict__ src, float2* __restrict__ dst,
                           const float2* __restrict__ tw) {
    __shared__ __align__(16) float2 xs[NN];
    __shared__ float2 tts[NN];
    __shared__ float2 S[25 * 21];
    int line = blockIdx.x;                 // kx
    const float2* s = src + (size_t)line * NN;     // R1T row kx, contiguous
    int t = threadIdx.x;
    for (int n = t; n < NN; n += 256) {
        xs[n] = s[n];
        float2 tt = tw[n];
        tts[n] = make_float2(tt.x, -tt.y);
    }
    __syncthreads();
    float2 o1, o2; int k;
    ct_dft_stages(xs, tts, S, t, &o1, &o2, &k);
    if (t < 250) {
        float2* dp = dst + (size_t)line * NN;      // EfT[kx][*], contiguous
        dp[k] = o1;
        dp[k + 250] = o2;
    }
}

// ---------------------------------------------------------------------------
// k_prop_mfma v7: grid (500 v, 2 zh) = 1000 blocks -> ~4 waves/SIMD (v6 had
// 2: latency-bound residue). Per block: 32 z x 64 nu output; 4 independent
// barrier-free waves each own a K-QUARTER (kappa 256w..256w+256, 16 K16-steps,
// gs = w*16+s), streaming B fragments directly from pre-swizzled Bg2
// (L2-resident) exactly as v6. 4-way K-merge via wave-private LDS slices
// (ctile4 overlaid on eft/kgs; barrier-separated). Full-line float4 stores.
//   A[z][2u+p] = {Re,Im}( EfT[v][u]*ASCALE * e^{i kg[v][u] z_z} )
// A-frag 32x32x16 (v5/v6-verified): row = lane&31 (z = zh*32+row), k = lk*8+e,
// u0 = gs*8 + lk*4. C layout (m74/m101): col = lane&31, row = (reg&3)+8*(reg>>2)+4*lk.
// ---------------------------------------------------------------------------
__global__ void __launch_bounds__(256)
k_prop_mfma(const float2* __restrict__ EfT,
            const float* __restrict__ kgamma,
            const float* __restrict__ zs,
            const _Float16* __restrict__ Bg2,
            float* __restrict__ part) {
    // 32768 B total: eft[512] f2 (4 KB) + kgs[512] f (2 KB) live during the
    // main loop; ctile4[4][2048] f overlays the whole buffer after a barrier.
    __shared__ __align__(16) char smem[4 * 2048 * 4];
    float2* eft = (float2*)smem;                 // [512]
    float*  kgs = (float*)(smem + 4096);         // [512]
    float*  ctile4 = (float*)smem;               // [4][2048] (post-barrier)

    int v = blockIdx.x;
    int zh = blockIdx.y;             // z-half: z = zh*32 + (lane&31)
    int t = threadIdx.x;
    int w = t >> 6;                  // wave 0..3 = K-quarter
    int lane = t & 63;
    int l31 = lane & 31;
    int lk = lane >> 5;              // kappa-oct selector 0/1

    for (int n = t; n < 512; n += 256) {
        if (n < NN) {
            float2 e = EfT[(size_t)v * NN + n];
            eft[n] = make_float2(e.x * ASCALE, e.y * ASCALE);  // fold ASCALE
            kgs[n] = kgamma[(size_t)v * NN + n];
        } else {
            eft[n] = make_float2(0.f, 0.f);
            kgs[n] = 0.f;
        }
    }
    float zv = zs[zh * 32 + l31];    // z of this lane's A rows
    __syncthreads();                 // eft/kgs ready; loop is barrier-free

    f32x16 acc[2] = {};              // 2 n-tiles (nu = nt*32 + l31)

#define MODSPLIT(ex, ey, kgv, i0) do {                                        \
        float s_, c_;                                                         \
        fast_sincos_red((kgv) * zv, &s_, &c_);                                \
        float yr = (ex) * c_ - (ey) * s_;                                     \
        float yi = (ex) * s_ + (ey) * c_;                                     \
        _Float16 h0 = (_Float16)yr;                                           \
        ah[i0] = h0; al[i0] = (_Float16)(yr - (float)h0);                     \
        _Float16 h1 = (_Float16)yi;                                           \
        ah[i0 + 1] = h1; al[i0 + 1] = (_Float16)(yi - (float)h1);             \
    } while (0)

    // this wave's K-quarter: gs = w*16 + s, fragments at Bg2 + gs*2048,
    // layout {bh0, bh1, bl0, bl1} x [lane][8]
    const _Float16* bbase = Bg2 + (size_t)(w * 16) * 2048 + (size_t)lane * 8;
#pragma unroll 4
    for (int s = 0; s < 16; ++s) {
        const _Float16* bs = bbase + (size_t)s * 2048;
        f16x8 bh0 = *(const f16x8*)(bs);
        f16x8 bh1 = *(const f16x8*)(bs + 512);
        f16x8 bl0 = *(const f16x8*)(bs + 1024);
        f16x8 bl1 = *(const f16x8*)(bs + 1536);
        int u0 = w * 128 + s * 8 + lk * 4;       // = gs*8 + lk*4 (broadcast)
        f16x8 ah, al;
        {
            float4 e01 = *(const float4*)&eft[u0];
            float4 e23 = *(const float4*)&eft[u0 + 2];
            float4 kg4 = *(const float4*)&kgs[u0];
            MODSPLIT(e01.x, e01.y, kg4.x, 0);
            MODSPLIT(e01.z, e01.w, kg4.y, 2);
            MODSPLIT(e23.x, e23.y, kg4.z, 4);
            MODSPLIT(e23.z, e23.w, kg4.w, 6);
        }
        acc[0] = __builtin_amdgcn_mfma_f32_32x32x16_f16(ah, bh0, acc[0], 0, 0, 0);
        acc[0] = __builtin_amdgcn_mfma_f32_32x32x16_f16(al, bh0, acc[0], 0, 0, 0);
        acc[0] = __builtin_amdgcn_mfma_f32_32x32x16_f16(ah, bl0, acc[0], 0, 0, 0);
        acc[1] = __builtin_amdgcn_mfma_f32_32x32x16_f16(ah, bh1, acc[1], 0, 0, 0);
        acc[1] = __builtin_amdgcn_mfma_f32_32x32x16_f16(al, bh1, acc[1], 0, 0, 0);
        acc[1] = __builtin_amdgcn_mfma_f32_32x32x16_f16(ah, bl1, acc[1], 0, 0, 0);
    }
#undef MODSPLIT

    // ---- 4-way K-merge via wave-private LDS slices ----
    __syncthreads();                 // all eft/kgs reads done (overlay safety)
    {
        float* slice = ctile4 + w * 2048;
#pragma unroll
        for (int nt = 0; nt < 2; ++nt)
#pragma unroll
            for (int reg = 0; reg < 16; ++reg) {
                int row = (reg & 3) + 8 * (reg >> 2) + 4 * lk;
                slice[row * 64 + nt * 32 + l31] = acc[nt][reg];
            }
    }
    __syncthreads();
    // ---- sum slices + write out: 16 lanes cover one full 256-B z-region ----
#pragma unroll
    for (int pass = 0; pass < 2; ++pass) {
        int idx = pass * 256 + t;     // 0..511, 4 floats each
        int i4 = idx * 4;
        int z = i4 >> 6, c4 = (i4 & 63) >> 2;
        float4 a0 = *(const float4*)&ctile4[i4];
        float4 a1 = *(const float4*)&ctile4[2048 + i4];
        float4 a2 = *(const float4*)&ctile4[4096 + i4];
        float4 a3 = *(const float4*)&ctile4[6144 + i4];
        float4 val = make_float4(a0.x + a1.x + a2.x + a3.x,
                                 a0.y + a1.y + a2.y + a3.y,
                                 a0.z + a1.z + a2.z + a3.z,
                                 a0.w + a1.w + a2.w + a3.w);
        *(float4*)&part[((size_t)(zh * 32 + z) * NN + v) * 64 + c4 * 4] = val;
    }
}

// ---------------------------------------------------------------------------
// B2: grid (4 line-groups, 64 z). Block (rq,z) handles ri in [8rq, 8rq+8)
// (rq=3: 7 useful). Per v it reads the one 64B line of part[z][v][16rq..+16)
// (coalesced; fetch == part size). Compute: 8 ri x 31 ci threads, 500-v
// twiddle recurrence re-seeded every 125 steps. inv carries the 1/64 A-scale
// compensation from k_prop_mfma.
// ---------------------------------------------------------------------------
__global__ void k_prop_cols(const float* __restrict__ part,
                            float* __restrict__ psf,
                            float* __restrict__ psf_sums) {
    __shared__ __align__(16) float X2[NN][16];   // 32000 B
    int rq = blockIdx.x;   // 0..3
    int z  = blockIdx.y;   // 0..63
    int t  = threadIdx.x;
    const float* p0 = part + ((size_t)z * NN) * 64 + rq * 16;
    for (int i = t; i < NN * 4; i += 256) {
        int v = i >> 2, q4 = i & 3;
        float4 a = *(const float4*)(p0 + (size_t)v * 64 + q4 * 4);
        *(float4*)&X2[v][q4 * 4] = a;
    }
    __syncthreads();
    int ril = t >> 5;            // 0..7
    int ri  = rq * 8 + ril;
    int ci  = t & 31;
    float val = 0.f;
    if (ri < PW && ci < PW) {
        int c = 235 + ci;
        float ar = 0.f, ai = 0.f;
        float sr, si;
        {
            float th = (TWO_PI_F / NN) * (float)(c % NN);
            sincosf(th, &si, &sr);
        }
        for (int vb = 0; vb < 4; ++vb) {       // exact re-seed every 125 steps
            int v0 = vb * 125;
            float wr, wi;
            float th = (TWO_PI_F / NN) * (float)((v0 * c) % NN);
            sincosf(th, &wi, &wr);
            for (int v = v0; v < v0 + 125; ++v) {
                float2 xy = *(const float2*)&X2[v][2 * ril];
                ar += xy.x * wr - xy.y * wi;
                ai += xy.x * wi + xy.y * wr;
                float nwr = wr * sr - wi * si;
                wi = wr * si + wi * sr;
                wr = nwr;
            }
        }
        const float inv = 64.0f / 250000.0f;   // 1/250000 * 64 (A-scale undo)
        float re = ar * inv, im = ai * inv;
        val = re * re + im * im;
        psf[(size_t)z * (PW * PW) + ri * PW + ci] = val;
    }
    // block sum -> psf_sums[z] (one atomic per wave)
#pragma unroll
    for (int m = 1; m < 64; m <<= 1) val += __shfl_xor(val, m);
    if ((t & 63) == 0) atomicAdd(&psf_sums[z], val);
}

// ---------------------------------------------------------------------------
__global__ void k_scatter(const float* __restrict__ psf,
                          const float* __restrict__ psf_sums,
                          const int* __restrict__ xyz,
                          float* __restrict__ canvas) {
    int e = blockIdx.x;
    int b = blockIdx.y;
    int r0 = xyz[(b * NE + e) * 2 + 0] - RR;
    int c0 = xyz[(b * NE + e) * 2 + 1] - RR;
    float sc = 1.0e6f / (psf_sums[e] + 1e-12f);
    float* cb = canvas + (size_t)b * (CAN * CAN);
    for (int p = threadIdx.x; p < PW * PW; p += blockDim.x) {
        int i = p / PW, j = p % PW;
        atomicAdd(cb + (r0 + i) * CAN + (c0 + j), psf[e * PW * PW + p] * sc);
    }
}

// ---------------------------------------------------------------------------
__global__ void k_final(const float* __restrict__ canvas,
                        const float* __restrict__ kern,
                        const float* __restrict__ eps_dark,
                        const float* __restrict__ eps_photon,
                        const float* __restrict__ eps_read,
                        float* __restrict__ out) {
    __shared__ float kk[49];
    __shared__ float tile[14][40];
    int b = blockIdx.z;
    int tx = threadIdx.x, ty = threadIdx.y;
    int t = ty * 32 + tx;
    int j0 = blockIdx.x * 32, i0 = blockIdx.y * 8;
    if (t < 49) kk[t] = kern[t];
    const float* cb = canvas + (size_t)b * (CAN * CAN);
    for (int p = t; p < 14 * 38; p += 256) {
        int rr = p / 38, cc = p % 38;
        int gi = i0 + rr - 2, gj = j0 + cc - 2;
        tile[rr][cc] = (gi >= 0 && gi < CAN && gj >= 0 && gj < CAN)
                           ? cb[gi * CAN + gj] : 0.f;
    }
    __syncthreads();
    int i = i0 + ty, j = j0 + tx;
    if (i >= OHW || j >= OHW) return;
    float acc = 0.f;
#pragma unroll
    for (int a = 0; a < 7; ++a)
#pragma unroll
        for (int q = 0; q < 7; ++q)
            acc += tile[ty + a][tx + q] * kk[a * 7 + q];
    int idx = b * (OHW * OHW) + i * OHW + j;
    float sig = acc * 0.9f;
    float dark = 0.005f + eps_dark[idx] * sqrtf(0.005f);
    float total = fmaxf(sig + dark, 0.0f);
    float noisy = total + eps_photon[idx] * sqrtf(fmaxf(total, 1e-12f));
    float elec = noisy + eps_read[idx] * 1.6f;
    float adu = fminf(fmaxf(elec * 2.0f, 0.0f), 65535.0f);
    float v = (adu <= 10.0f) ? 1.0f : fminf(adu, 4.0e9f);
    out[idx] = v / 4.0e9f;
}

// ---------------------------------------------------------------------------
extern "C" void kernel_launch(void* const* d_in, const int* in_sizes, int n_in,
                              void* d_out, int out_size, void* d_ws, size_t ws_size,
                              hipStream_t stream) {
    const float* phase    = (const float*)d_in[0];
    const float* zs       = (const float*)d_in[1];
    const int*   xyz      = (const int*)d_in[2];
    const float* std_u    = (const float*)d_in[3];
    const float* epsd     = (const float*)d_in[4];
    const float* epsp     = (const float*)d_in[5];
    const float* epsr     = (const float*)d_in[6];
    float* out = (float*)d_out;

    char* ws = (char*)d_ws;
    size_t off = 0;
    auto alloc = [&](size_t bytes) {
        off = (off + 255) & ~(size_t)255;
        size_t o = off; off += bytes; return o;
    };
    float*  kgamma   = (float*) (ws + alloc((size_t)NN * NN * 4));
    float2* tw       = (float2*)(ws + alloc((size_t)NN * 8));
    float2* R1T      = (float2*)(ws + alloc((size_t)NN * NN * 8));
    float2* EfT      = (float2*)(ws + alloc((size_t)NN * NN * 8));
    float*  part     = (float*) (ws + alloc((size_t)NE * NN * 64 * 4));  // 8.2 MB
    float*  psf      = (float*) (ws + alloc((size_t)NE * PW * PW * 4));
    float*  psf_sums = (float*) (ws + alloc((size_t)NE * 4));
    float*  kern     = (float*) (ws + alloc((size_t)64 * 4));
    float*  canvas   = (float*) (ws + alloc((size_t)BATCH * CAN * CAN * 4));
    _Float16* Bg2    = (_Float16*)(ws + alloc((size_t)BG2_F16 * 2));     // 256 KB
    (void)ws_size; (void)n_in; (void)in_sizes; (void)out_size;

    // grid covers max(NN*NN, SETUP_N) = SETUP_N = 320113 (incl. Bg2 gen)
    k_setup<<<(SETUP_N + 255) / 256, 256, 0, stream>>>(
        std_u, kgamma, tw, kern, canvas, psf_sums, Bg2);
    // fft2: rows (fused field gen, writes transposed) then cols (contiguous)
    k_dft_rows<<<NN, 256, 0, stream>>>(phase, R1T, tw);
    k_dft_cols<<<NN, 256, 0, stream>>>(R1T, EfT, tw);
    // partial inverse transforms: (v, z-half) blocks, K-quarter per wave
    k_prop_mfma<<<dim3(NN, 2), 256, 0, stream>>>(EfT, kgamma, zs, Bg2, part);
    k_prop_cols<<<dim3(4, NE), 256, 0, stream>>>(part, psf, psf_sums);
    k_scatter<<<dim3(NE, BATCH), 256, 0, stream>>>(psf, psf_sums, xyz, canvas);
    k_final<<<dim3((OHW + 31) / 32, (OHW + 7) / 8, BATCH), dim3(32, 8), 0, stream>>>(
        canvas, kern, epsd, epsp, epsr, out);
}

// Round 8
// 134.896 us; speedup vs baseline: 1.2170x; 1.0108x over previous
//
#include <hip/hip_runtime.h>
#include <math.h>

#define NN 500
#define NE 64
#define BATCH 8
#define RR 15
#define PW 31            // 2R+1
#define CAN 200
#define OHW 198
#define TWO_PI_F 6.28318530717958647692f
// k_setup must cover canvas (320000) + psf_sums (64) + kern (49) AND NN*NN.
#define SETUP_N (BATCH * CAN * CAN + NE + 49)

// --- MFMA prop parameters ---------------------------------------------------
// kappa = 2u + p (p=0 re, p=1 im), u padded 500->512 => K = 1024 = 64 K16-steps
// Bg2: B fragments PRE-SWIZZLED in per-lane order for mfma_f32_32x32x16_f16:
//   [gs=0..63][plane hi/lo][nt 0..1][lane 0..63][e 0..7] f16   (256 KB)
//   kappa = gs*16 + (lane>>5)*8 + e ;  nu = nt*32 + (lane&31)
// A wave's fragment load = global_load_dwordx4 of 64 lanes x 16 B contiguous.
#define BG2_F16 (64 * 2 * 2 * 64 * 8)   // 131072 f16 = 256 KB
#define ASCALE (1.0f / 64.0f)      // A pre-scale (f16 range safety); undone in k_prop_cols
// part: [z][v][64 nu] floats — nu fastest, 62 useful + 2 pad = 256 B region

using f16x8 = __attribute__((ext_vector_type(8))) _Float16;
using f32x16 = __attribute__((ext_vector_type(16))) float;

// Fast accurate sincos for |theta| up to ~1200 rad: Cody-Waite 2-term
// reduction + hardware v_sin/v_cos on the reduced |r| <= pi argument.
__device__ __forceinline__ void fast_sincos_red(float theta, float* s, float* c) {
    const float INV2PI = 0.15915494309189535f;
    const float PI2_HI = 6.28318548202514648f;   // f32(2*pi)
    const float PI2_LO = -1.7484556e-7f;         // 2*pi - PI2_HI
    float n = rintf(theta * INV2PI);
    float r = fmaf(n, -PI2_HI, theta);
    r = fmaf(n, -PI2_LO, r);
    *s = __sinf(r);
    *c = __cosf(r);
}

// ---------------------------------------------------------------------------
// K_setup: K*GAMMA table (f64 sqrt path), 500-pt twiddle table, blur-kernel
// coefficients, canvas+psf_sums zero, AND the fragment-order f16 hi/lo
// twiddle matrix Bg2 for the MFMA partial-IDFT:
//   B[kappa][nu]: kappa = 2u+p, nu = 2*(r-235)+q (q=0 re-col, q=1 im-col)
//     q=0: p=0 ->  W.re   p=1 -> -W.im
//     q=1: p=0 ->  W.im   p=1 ->  W.re        (W = e^{+2pi i u r / 500})
// GRID MUST COVER SETUP_N.
// ---------------------------------------------------------------------------
__global__ void k_setup(const float* __restrict__ std_u,
                        float* __restrict__ kgamma,
                        float2* __restrict__ tw,
                        float* __restrict__ kern,
                        float* __restrict__ canvas,
                        float* __restrict__ psf_sums,
                        _Float16* __restrict__ Bg2) {
    int idx = blockIdx.x * blockDim.x + threadIdx.x;
    if (idx < NN) {
        double th = 2.0 * M_PI * (double)idx / (double)NN;
        tw[idx] = make_float2((float)cos(th), (float)sin(th));
    }
    if (idx < BG2_F16) {   // fragment-order Bg2 generation
        int e = idx & 7;
        int lane = (idx >> 3) & 63;
        int nt = (idx >> 9) & 1;
        int plane = (idx >> 10) & 1;
        int gs = idx >> 11;            // 0..63
        int kap = gs * 16 + (lane >> 5) * 8 + e;
        int nu = nt * 32 + (lane & 31);
        float outv = 0.f;
        if (kap < 2 * NN) {
            int u = kap >> 1, p = kap & 1;
            int ri = nu >> 1, q = nu & 1;
            int r = 235 + ri;          // ri=31 -> dummy col pair (never read)
            int m = (u * r) % NN;
            double th = 2.0 * M_PI * (double)m / (double)NN;
            double wre = cos(th), wim = sin(th);
            double val = (q == 0) ? ((p == 0) ? wre : -wim)
                                  : ((p == 0) ? wim : wre);
            float x = (float)val;
            _Float16 h = (_Float16)x;
            outv = (plane == 0) ? (float)h : (x - (float)h);
        }
        Bg2[idx] = (_Float16)outv;
    }
    if (idx < BATCH * CAN * CAN) canvas[idx] = 0.f;
    if (idx >= BATCH * CAN * CAN && idx < BATCH * CAN * CAN + NE)
        psf_sums[idx - BATCH * CAN * CAN] = 0.f;
    if (idx >= BATCH * CAN * CAN + NE && idx < SETUP_N) {
        int t = idx - (BATCH * CAN * CAN + NE);
        float stdv = 0.8f + 0.4f * std_u[0];
        float s2 = stdv * stdv;
        int a = t / 7 - 3, b = t % 7 - 3;
        float g = (float)exp(-0.5 * (double)(a * a + b * b));
        kern[t] = (1.0f / (2.0f * (float)M_PI * s2)) * powf(g, 1.0f / s2);
    }
    if (idx >= NN * NN) return;
    int i = idx / NN, j = idx % NN;
    double fy = (double)((i < 250) ? i : i - 500) * 2000.0;
    double fx = (double)((j < 250) ? j : j - 500) * 2000.0;
    double a = 5.32e-7 * fx;
    double b = 5.32e-7 * fy;
    double g = 1.0 - a * a - b * b;
    g = (g > 0.0) ? sqrt(g) : 0.0;
    float Kf = (float)(2.0 * M_PI * 1.0 / 5.32e-7);
    kgamma[idx] = Kf * (float)g;
}

// ---------------------------------------------------------------------------
// 500-pt forward DFT via Cooley-Tukey 20x25. Shared stages helper.
// ---------------------------------------------------------------------------
__device__ __forceinline__ void ct_dft_stages(const float2* xs, const float2* tts,
                                              float2* S, int t,
                                              float2* out1, float2* out2, int* kout) {
    if (t < 250) {
        int d = t / 25;
        int b = t % 25;
        float2 st = tts[(25 * d) % NN];
        float wr = 1.f, wi = 0.f;
        float Er = 0.f, Ei = 0.f, Or_ = 0.f, Oi = 0.f;
#pragma unroll
        for (int a = 0; a < 20; a += 2) {
            float2 x0 = xs[25 * a + b];
            Er += x0.x * wr - x0.y * wi;
            Ei += x0.x * wi + x0.y * wr;
            float nr = wr * st.x - wi * st.y;
            float ni = wr * st.y + wi * st.x;
            float2 x1 = xs[25 * (a + 1) + b];
            Or_ += x1.x * nr - x1.y * ni;
            Oi  += x1.x * ni + x1.y * nr;
            wr = nr * st.x - ni * st.y;
            wi = nr * st.y + ni * st.x;
        }
        S[b * 21 + d]      = make_float2(Er + Or_, Ei + Oi);
        S[b * 21 + d + 10] = make_float2(Er - Or_, Ei - Oi);
    }
    __syncthreads();
    if (t < 250) {
        int k = t;
        int d1 = k % 20;
        int d2 = (d1 + 10) % 20;
        float2 s1 = tts[k];
        float wr = 1.f, wi = 0.f;
        float a1r = 0.f, a1i = 0.f, a2r = 0.f, a2i = 0.f;
#pragma unroll
        for (int b = 0; b < 25; ++b) {
            float2 u1 = S[b * 21 + d1];
            float2 u2 = S[b * 21 + d2];
            a1r += u1.x * wr - u1.y * wi;
            a1i += u1.x * wi + u1.y * wr;
            float sgnb = (b & 1) ? -1.f : 1.f;
            float w2r = sgnb * wr, w2i = sgnb * wi;
            a2r += u2.x * w2r - u2.y * w2i;
            a2i += u2.x * w2i + u2.y * w2r;
            float nr = wr * s1.x - wi * s1.y;
            wi = wr * s1.y + wi * s1.x;
            wr = nr;
        }
        *out1 = make_float2(a1r, a1i);
        *out2 = make_float2(a2r, a2i);
        *kout = k;
    }
}

// k_dft_rows: fused pupil-field generation (f32) + row DFT; writes R1T[k][y].
__global__ void k_dft_rows(const float* __restrict__ phase, float2* __restrict__ dst,
                           const float2* __restrict__ tw) {
    __shared__ __align__(16) float2 xs[NN];
    __shared__ float2 tts[NN];
    __shared__ float2 S[25 * 21];
    int line = blockIdx.x;                 // y index i
    int t = threadIdx.x;
    const float INV2SIG = 2.2222222e7f;              // 1/(2*(1.5e-4)^2)
    const float C1M = (float)(M_PI / 5.32e-8);       // pi/(WL*FL)
    float y = (float)(line - 250) * 1e-6f;
    float y2 = y * y;
    const float* prow = phase + (size_t)line * NN;
    for (int n = t; n < NN; n += 256) {
        float x = (float)(n - 250) * 1e-6f;
        float r2 = x * x + y2;
        float inc = __expf(-r2 * INV2SIG);
        float c1 = C1M * r2;
        float b1r = __cosf(c1), b1i = -__sinf(c1);
        float ph = prow[n];
        float sp = __sinf(ph), cp = __cosf(ph);
        float ar = inc * cp, ai = inc * sp;
        xs[n] = make_float2(ar * b1r - ai * b1i, ar * b1i + ai * b1r);
        float2 tt = tw[n];
        tts[n] = make_float2(tt.x, -tt.y);   // forward
    }
    __syncthreads();
    float2 o1, o2; int k;
    ct_dft_stages(xs, tts, S, t, &o1, &o2, &k);
    if (t < 250) {
        dst[(size_t)k * NN + line] = o1;           // R1T[k][y]
        dst[(size_t)(k + 250) * NN + line] = o2;
    }
}

// ---------------------------------------------------------------------------
// k_dft_prop (fused k_dft_cols + k_prop_mfma v6): one block per v=kx line.
// Phase 1: column DFT of R1T row v (contiguous) -> EfT line held in LDS eft[]
//   directly from registers (ASCALE folded) — the EfT global buffer, its
//   2 MB write + 2 MB read, the prop prologue, and one launch are deleted.
// Phase 2: v6 prop structure — 4 barrier-free waves (wh = K-half, mw =
//   z-half), B fragments streamed directly from pre-swizzled Bg2 (L2-res),
//   2-way K-merge in LDS ctile (overlays the DFT scratch; fenced by the
//   post-eft barrier), full-line float4 stores to part[z][v][64].
//   A[z][2u+p] = {Re,Im}( EfT[v][u]*ASCALE * e^{i kg[v][u] z_z} )
// A-frag 32x32x16 (v5/v6-verified): row = lane&31 (z = mw*32+row), k = lk*8+e,
// u0 = wh*256 + s*8 + lk*4. C layout (m74/m101): col = lane&31,
// row = (reg&3)+8*(reg>>2)+4*lk.
// ---------------------------------------------------------------------------
__global__ void __launch_bounds__(256)
k_dft_prop(const float2* __restrict__ R1T,
           const float* __restrict__ kgamma,
           const float* __restrict__ zs,
           const float2* __restrict__ tw,
           const _Float16* __restrict__ Bg2,
           float* __restrict__ part) {
    // region A [0,16384): DFT scratch xs(4000)|tts(4000)|S(4200), later ctile
    // region B [16384,22528): eft[512] f2 (4096) + kgs[512] f (2048)
    __shared__ __align__(16) char smem[22528];
    float2* xs    = (float2*)smem;              // [500]
    float2* tts   = (float2*)(smem + 4000);     // [500]
    float2* S     = (float2*)(smem + 8000);     // [525]
    float*  ctile = (float*)smem;               // [64][64] post-barrier overlay
    float2* eft   = (float2*)(smem + 16384);    // [512]
    float*  kgs   = (float*)(smem + 20480);     // [512]

    int v = blockIdx.x;
    int t = threadIdx.x;

    // ---- phase 0: loads ----
    const float2* srow = R1T + (size_t)v * NN;   // contiguous
    for (int n = t; n < NN; n += 256) {
        xs[n] = srow[n];
        float2 tt = tw[n];
        tts[n] = make_float2(tt.x, -tt.y);       // forward
    }
    for (int n = t; n < 512; n += 256) {
        kgs[n] = (n < NN) ? kgamma[(size_t)v * NN + n] : 0.f;
        if (n >= NN) eft[n] = make_float2(0.f, 0.f);   // zero-pad u=500..511
    }
    __syncthreads();

    // ---- phase 1: column DFT (internal barrier in helper) ----
    float2 o1, o2; int k;
    ct_dft_stages(xs, tts, S, t, &o1, &o2, &k);
    if (t < 250) {
        eft[k]       = make_float2(o1.x * ASCALE, o1.y * ASCALE);
        eft[k + 250] = make_float2(o2.x * ASCALE, o2.y * ASCALE);
    }
    __syncthreads();   // eft ready; also fences all S/xs/tts reads (overlay)

    // ---- phase 2: prop (v6 structure, barrier-free loop) ----
    int w = t >> 6;                  // wave 0..3
    int wh = w >> 1;                 // K-half 0/1 (kappa 512*wh ..)
    int mw = w & 1;                  // z-half: rows 32*mw..32*mw+31
    int lane = t & 63;
    int l31 = lane & 31;
    int lk = lane >> 5;              // kappa-oct selector 0/1
    float zv = zs[mw * 32 + l31];    // z of this lane's A rows

    f32x16 acc[2] = {};              // 2 n-tiles (nu = nt*32 + l31)

#define MODSPLIT(ex, ey, kgv, i0) do {                                        \
        float s_, c_;                                                         \
        fast_sincos_red((kgv) * zv, &s_, &c_);                                \
        float yr = (ex) * c_ - (ey) * s_;                                     \
        float yi = (ex) * s_ + (ey) * c_;                                     \
        _Float16 h0 = (_Float16)yr;                                           \
        ah[i0] = h0; al[i0] = (_Float16)(yr - (float)h0);                     \
        _Float16 h1 = (_Float16)yi;                                           \
        ah[i0 + 1] = h1; al[i0 + 1] = (_Float16)(yi - (float)h1);             \
    } while (0)

    // this wave's K-half: gs = wh*32 + s, fragments at Bg2 + gs*2048,
    // layout {bh0, bh1, bl0, bl1} x [lane][8]
    const _Float16* bbase = Bg2 + (size_t)(wh * 32) * 2048 + (size_t)lane * 8;
#pragma unroll 4
    for (int s = 0; s < 32; ++s) {
        const _Float16* bs = bbase + (size_t)s * 2048;
        f16x8 bh0 = *(const f16x8*)(bs);
        f16x8 bh1 = *(const f16x8*)(bs + 512);
        f16x8 bl0 = *(const f16x8*)(bs + 1024);
        f16x8 bl1 = *(const f16x8*)(bs + 1536);
        int u0 = wh * 256 + s * 8 + lk * 4;      // this lane's 4 u's (broadcast)
        f16x8 ah, al;
        {
            float4 e01 = *(const float4*)&eft[u0];
            float4 e23 = *(const float4*)&eft[u0 + 2];
            float4 kg4 = *(const float4*)&kgs[u0];
            MODSPLIT(e01.x, e01.y, kg4.x, 0);
            MODSPLIT(e01.z, e01.w, kg4.y, 2);
            MODSPLIT(e23.x, e23.y, kg4.z, 4);
            MODSPLIT(e23.z, e23.w, kg4.w, 6);
        }
        acc[0] = __builtin_amdgcn_mfma_f32_32x32x16_f16(ah, bh0, acc[0], 0, 0, 0);
        acc[0] = __builtin_amdgcn_mfma_f32_32x32x16_f16(al, bh0, acc[0], 0, 0, 0);
        acc[0] = __builtin_amdgcn_mfma_f32_32x32x16_f16(ah, bl0, acc[0], 0, 0, 0);
        acc[1] = __builtin_amdgcn_mfma_f32_32x32x16_f16(ah, bh1, acc[1], 0, 0, 0);
        acc[1] = __builtin_amdgcn_mfma_f32_32x32x16_f16(al, bh1, acc[1], 0, 0, 0);
        acc[1] = __builtin_amdgcn_mfma_f32_32x32x16_f16(ah, bl1, acc[1], 0, 0, 0);
    }
#undef MODSPLIT

    // ---- merge K-halves in LDS (ctile overlays DFT scratch; fenced) ----
    __syncthreads();                 // all eft/kgs reads done before overlay
    if (wh == 0) {
#pragma unroll
        for (int nt = 0; nt < 2; ++nt)
#pragma unroll
            for (int reg = 0; reg < 16; ++reg) {
                int row = (reg & 3) + 8 * (reg >> 2) + 4 * lk;
                ctile[(mw * 32 + row) * 64 + nt * 32 + l31] = acc[nt][reg];
            }
    }
    __syncthreads();
    if (wh == 1) {
#pragma unroll
        for (int nt = 0; nt < 2; ++nt)
#pragma unroll
            for (int reg = 0; reg < 16; ++reg) {
                int row = (reg & 3) + 8 * (reg >> 2) + 4 * lk;
                ctile[(mw * 32 + row) * 64 + nt * 32 + l31] += acc[nt][reg];
            }
    }
    __syncthreads();
    // ---- write out: 16 consecutive lanes cover one full 256-B z-region ----
#pragma unroll
    for (int p = 0; p < 4; ++p) {
        int idx = p * 256 + t;        // 0..1023
        int z = idx >> 4, c4 = idx & 15;
        float4 val = *(const float4*)&ctile[z * 64 + c4 * 4];
        *(float4*)&part[((size_t)z * NN + v) * 64 + c4 * 4] = val;
    }
}

// ---------------------------------------------------------------------------
// B2: grid (4 line-groups, 64 z). Block (rq,z) handles ri in [8rq, 8rq+8)
// (rq=3: 7 useful). Per v it reads the one 64B line of part[z][v][16rq..+16)
// (coalesced; fetch == part size). Compute: 8 ri x 31 ci threads, 500-v
// twiddle recurrence re-seeded every 125 steps. inv carries the 1/64 A-scale
// compensation from k_dft_prop.
// ---------------------------------------------------------------------------
__global__ void k_prop_cols(const float* __restrict__ part,
                            float* __restrict__ psf,
                            float* __restrict__ psf_sums) {
    __shared__ __align__(16) float X2[NN][16];   // 32000 B
    int rq = blockIdx.x;   // 0..3
    int z  = blockIdx.y;   // 0..63
    int t  = threadIdx.x;
    const float* p0 = part + ((size_t)z * NN) * 64 + rq * 16;
    for (int i = t; i < NN * 4; i += 256) {
        int v = i >> 2, q4 = i & 3;
        float4 a = *(const float4*)(p0 + (size_t)v * 64 + q4 * 4);
        *(float4*)&X2[v][q4 * 4] = a;
    }
    __syncthreads();
    int ril = t >> 5;            // 0..7
    int ri  = rq * 8 + ril;
    int ci  = t & 31;
    float val = 0.f;
    if (ri < PW && ci < PW) {
        int c = 235 + ci;
        float ar = 0.f, ai = 0.f;
        float sr, si;
        {
            float th = (TWO_PI_F / NN) * (float)(c % NN);
            sincosf(th, &si, &sr);
        }
        for (int vb = 0; vb < 4; ++vb) {       // exact re-seed every 125 steps
            int v0 = vb * 125;
            float wr, wi;
            float th = (TWO_PI_F / NN) * (float)((v0 * c) % NN);
            sincosf(th, &wi, &wr);
            for (int v = v0; v < v0 + 125; ++v) {
                float2 xy = *(const float2*)&X2[v][2 * ril];
                ar += xy.x * wr - xy.y * wi;
                ai += xy.x * wi + xy.y * wr;
                float nwr = wr * sr - wi * si;
                wi = wr * si + wi * sr;
                wr = nwr;
            }
        }
        const float inv = 64.0f / 250000.0f;   // 1/250000 * 64 (A-scale undo)
        float re = ar * inv, im = ai * inv;
        val = re * re + im * im;
        psf[(size_t)z * (PW * PW) + ri * PW + ci] = val;
    }
    // block sum -> psf_sums[z] (one atomic per wave)
#pragma unroll
    for (int m = 1; m < 64; m <<= 1) val += __shfl_xor(val, m);
    if ((t & 63) == 0) atomicAdd(&psf_sums[z], val);
}

// ---------------------------------------------------------------------------
__global__ void k_scatter(const float* __restrict__ psf,
                          const float* __restrict__ psf_sums,
                          const int* __restrict__ xyz,
                          float* __restrict__ canvas) {
    int e = blockIdx.x;
    int b = blockIdx.y;
    int r0 = xyz[(b * NE + e) * 2 + 0] - RR;
    int c0 = xyz[(b * NE + e) * 2 + 1] - RR;
    float sc = 1.0e6f / (psf_sums[e] + 1e-12f);
    float* cb = canvas + (size_t)b * (CAN * CAN);
    for (int p = threadIdx.x; p < PW * PW; p += blockDim.x) {
        int i = p / PW, j = p % PW;
        atomicAdd(cb + (r0 + i) * CAN + (c0 + j), psf[e * PW * PW + p] * sc);
    }
}

// ---------------------------------------------------------------------------
__global__ void k_final(const float* __restrict__ canvas,
                        const float* __restrict__ kern,
                        const float* __restrict__ eps_dark,
                        const float* __restrict__ eps_photon,
                        const float* __restrict__ eps_read,
                        float* __restrict__ out) {
    __shared__ float kk[49];
    __shared__ float tile[14][40];
    int b = blockIdx.z;
    int tx = threadIdx.x, ty = threadIdx.y;
    int t = ty * 32 + tx;
    int j0 = blockIdx.x * 32, i0 = blockIdx.y * 8;
    if (t < 49) kk[t] = kern[t];
    const float* cb = canvas + (size_t)b * (CAN * CAN);
    for (int p = t; p < 14 * 38; p += 256) {
        int rr = p / 38, cc = p % 38;
        int gi = i0 + rr - 2, gj = j0 + cc - 2;
        tile[rr][cc] = (gi >= 0 && gi < CAN && gj >= 0 && gj < CAN)
                           ? cb[gi * CAN + gj] : 0.f;
    }
    __syncthreads();
    int i = i0 + ty, j = j0 + tx;
    if (i >= OHW || j >= OHW) return;
    float acc = 0.f;
#pragma unroll
    for (int a = 0; a < 7; ++a)
#pragma unroll
        for (int q = 0; q < 7; ++q)
            acc += tile[ty + a][tx + q] * kk[a * 7 + q];
    int idx = b * (OHW * OHW) + i * OHW + j;
    float sig = acc * 0.9f;
    float dark = 0.005f + eps_dark[idx] * sqrtf(0.005f);
    float total = fmaxf(sig + dark, 0.0f);
    float noisy = total + eps_photon[idx] * sqrtf(fmaxf(total, 1e-12f));
    float elec = noisy + eps_read[idx] * 1.6f;
    float adu = fminf(fmaxf(elec * 2.0f, 0.0f), 65535.0f);
    float v = (adu <= 10.0f) ? 1.0f : fminf(adu, 4.0e9f);
    out[idx] = v / 4.0e9f;
}

// ---------------------------------------------------------------------------
extern "C" void kernel_launch(void* const* d_in, const int* in_sizes, int n_in,
                              void* d_out, int out_size, void* d_ws, size_t ws_size,
                              hipStream_t stream) {
    const float* phase    = (const float*)d_in[0];
    const float* zs       = (const float*)d_in[1];
    const int*   xyz      = (const int*)d_in[2];
    const float* std_u    = (const float*)d_in[3];
    const float* epsd     = (const float*)d_in[4];
    const float* epsp     = (const float*)d_in[5];
    const float* epsr     = (const float*)d_in[6];
    float* out = (float*)d_out;

    char* ws = (char*)d_ws;
    size_t off = 0;
    auto alloc = [&](size_t bytes) {
        off = (off + 255) & ~(size_t)255;
        size_t o = off; off += bytes; return o;
    };
    float*  kgamma   = (float*) (ws + alloc((size_t)NN * NN * 4));
    float2* tw       = (float2*)(ws + alloc((size_t)NN * 8));
    float2* R1T      = (float2*)(ws + alloc((size_t)NN * NN * 8));
    float*  part     = (float*) (ws + alloc((size_t)NE * NN * 64 * 4));  // 8.2 MB
    float*  psf      = (float*) (ws + alloc((size_t)NE * PW * PW * 4));
    float*  psf_sums = (float*) (ws + alloc((size_t)NE * 4));
    float*  kern     = (float*) (ws + alloc((size_t)64 * 4));
    float*  canvas   = (float*) (ws + alloc((size_t)BATCH * CAN * CAN * 4));
    _Float16* Bg2    = (_Float16*)(ws + alloc((size_t)BG2_F16 * 2));     // 256 KB
    (void)ws_size; (void)n_in; (void)in_sizes; (void)out_size;

    // grid covers max(NN*NN, SETUP_N) = SETUP_N = 320113 (incl. Bg2 gen)
    k_setup<<<(SETUP_N + 255) / 256, 256, 0, stream>>>(
        std_u, kgamma, tw, kern, canvas, psf_sums, Bg2);
    // fft2 rows (fused field gen, writes transposed)
    k_dft_rows<<<NN, 256, 0, stream>>>(phase, R1T, tw);
    // fused: column DFT + MFMA partial inverse transform (EfT eliminated)
    k_dft_prop<<<NN, 256, 0, stream>>>(R1T, kgamma, zs, tw, Bg2, part);
    k_prop_cols<<<dim3(4, NE), 256, 0, stream>>>(part, psf, psf_sums);
    k_scatter<<<dim3(NE, BATCH), 256, 0, stream>>>(psf, psf_sums, xyz, canvas);
    k_final<<<dim3((OHW + 31) / 32, (OHW + 7) / 8, BATCH), dim3(32, 8), 0, stream>>>(
        canvas, kern, epsd, epsp, epsr, out);
}